// Round 2
// baseline (841.122 us; speedup 1.0000x reference)
//
#include <hip/hip_runtime.h>
#include <hip/hip_fp16.h>

// MPA_16698832847132 — round 1: fix conv2 LDS staging bound (4624 -> 9248).
// Pipeline: [gemm_bt f32->bf16 qkv] [conv1 half2] [conv2 half2] [attn bf16-MFMA fused] [gemm_bt f32 proj]
// Workspace layout (needs 134,479,872 B):
//   qkv bf16 [8192][1536]          @ 0          (25,165,824 B)
//   w   f32  [8][1024][1024]       @ 25,165,824 (33,554,432 B)
//   y1  f16  [1024][1156][32]      @ 58,720,256 (75,759,616 B)   } overlapped:
//   oh  f32  [8192][512]           @ 58,720,256 (16,777,216 B)   } y1 dead after conv2

typedef __attribute__((ext_vector_type(8))) short bf16x8;
typedef __attribute__((ext_vector_type(4))) float f32x4;

__device__ __forceinline__ unsigned short f2bf(float f) {
  unsigned u = __builtin_bit_cast(unsigned, f);
  u += 0x7FFFu + ((u >> 16) & 1u);
  return (unsigned short)(u >> 16);
}

// ---------------- C[M][N] = A[M][K] * B[N][K]^T (+bias); 128x128 tile, BK=8 ----
template<bool OUT_BF16>
__global__ __launch_bounds__(256) void gemm_bt(
    const float* __restrict__ A, const float* __restrict__ B,
    void* __restrict__ Cv, const float* __restrict__ bias,
    int M, int N, int K)
{
  __shared__ __align__(16) float As[8][132];
  __shared__ __align__(16) float Bs[8][132];
  const int tid = threadIdx.x;
  const int m0 = blockIdx.y * 128, n0 = blockIdx.x * 128;
  const int ty = tid >> 4, tx = tid & 15;
  float acc[2][2][4][4];
#pragma unroll
  for (int a = 0; a < 2; a++)
#pragma unroll
    for (int b = 0; b < 2; b++)
#pragma unroll
      for (int i = 0; i < 4; i++)
#pragma unroll
        for (int j = 0; j < 4; j++) acc[a][b][i][j] = 0.f;

  const int r = tid >> 1, kq = (tid & 1) * 4;
  const float* Ap = A + (size_t)(m0 + r) * K + kq;
  const float* Bp = B + (size_t)(n0 + r) * K + kq;

  for (int k0 = 0; k0 < K; k0 += 8) {
    float4 av = *(const float4*)(Ap + k0);
    float4 bv = *(const float4*)(Bp + k0);
    __syncthreads();
    As[kq + 0][r] = av.x; As[kq + 1][r] = av.y; As[kq + 2][r] = av.z; As[kq + 3][r] = av.w;
    Bs[kq + 0][r] = bv.x; Bs[kq + 1][r] = bv.y; Bs[kq + 2][r] = bv.z; Bs[kq + 3][r] = bv.w;
    __syncthreads();
#pragma unroll
    for (int kk = 0; kk < 8; kk++) {
      float4 a0 = *(const float4*)&As[kk][ty * 4];
      float4 a1 = *(const float4*)&As[kk][64 + ty * 4];
      float4 b0 = *(const float4*)&Bs[kk][tx * 4];
      float4 b1 = *(const float4*)&Bs[kk][64 + tx * 4];
      float ar[2][4] = {{a0.x, a0.y, a0.z, a0.w}, {a1.x, a1.y, a1.z, a1.w}};
      float br[2][4] = {{b0.x, b0.y, b0.z, b0.w}, {b1.x, b1.y, b1.z, b1.w}};
#pragma unroll
      for (int rh = 0; rh < 2; rh++)
#pragma unroll
        for (int i = 0; i < 4; i++)
#pragma unroll
          for (int ch = 0; ch < 2; ch++)
#pragma unroll
            for (int j = 0; j < 4; j++)
              acc[rh][ch][i][j] = fmaf(ar[rh][i], br[ch][j], acc[rh][ch][i][j]);
    }
  }

#pragma unroll
  for (int rh = 0; rh < 2; rh++)
#pragma unroll
    for (int i = 0; i < 4; i++) {
      const int row = m0 + rh * 64 + ty * 4 + i;
#pragma unroll
      for (int ch = 0; ch < 2; ch++) {
        const int col = n0 + ch * 64 + tx * 4;
        float v0 = acc[rh][ch][i][0], v1 = acc[rh][ch][i][1];
        float v2 = acc[rh][ch][i][2], v3 = acc[rh][ch][i][3];
        if (bias) { v0 += bias[col]; v1 += bias[col + 1]; v2 += bias[col + 2]; v3 += bias[col + 3]; }
        if (OUT_BF16) {
          unsigned long long u = (unsigned long long)f2bf(v0)
                               | ((unsigned long long)f2bf(v1) << 16)
                               | ((unsigned long long)f2bf(v2) << 32)
                               | ((unsigned long long)f2bf(v3) << 48);
          *(unsigned long long*)((unsigned short*)Cv + (size_t)row * N + col) = u;
        } else {
          float4 o; o.x = v0; o.y = v1; o.z = v2; o.w = v3;
          *(float4*)((float*)Cv + (size_t)row * N + col) = o;
        }
      }
    }
}

// ---------------- conv1 3x3 (32->32ch, 36^2 -> 34^2) + instancenorm + relu ----
// one image per block; input staged channel-inner half2; y1 out [img][pix][ic] f16
__global__ __launch_bounds__(256) void conv1_kernel(
    const float* __restrict__ rpe, const float* __restrict__ c1w,
    const float* __restrict__ g1, const float* __restrict__ b1,
    __half* __restrict__ y1)
{
  extern __shared__ __align__(16) char smem[];
  __half* inH = (__half*)smem;                          // [1296][36] (32 used + pad)
  __half* wH  = (__half*)(smem + 1296 * 36 * 2);        // [9][32][32] (tap, oc, ic)
  float* gb   = (float*)(smem + 1296 * 36 * 2 + 9216 * 2); // 64: g1|b1
  float* red  = gb + 64;                                // 64: 4 waves x 16
  const int tid = threadIdx.x;
  const int p = blockIdx.x;

  const float* src = rpe + (size_t)(((p >> 5) + 2) * 36 + (p & 31) + 2) * 41472;
  for (int t = tid; t < 10368; t += 256) {
    int pix = t >> 3, dq = (t & 7) << 2;
    float4 v = *(const float4*)(src + pix * 32 + dq);
    __half2* dst = (__half2*)(inH + pix * 36 + dq);
    dst[0] = __floats2half2_rn(v.x, v.y);
    dst[1] = __floats2half2_rn(v.z, v.w);
  }
  for (int t = tid; t < 9216; t += 256) {
    int oc = t / 288, rem = t - oc * 288;
    int ic = rem / 9, tap = rem - ic * 9;
    wH[(tap * 32 + oc) * 32 + ic] = __float2half(c1w[t]);
  }
  if (tid < 32) { gb[tid] = g1[tid]; gb[32 + tid] = b1[tid]; }
  __syncthreads();

  int ib[5]; int pvalid[5];
#pragma unroll
  for (int i = 0; i < 5; i++) {
    int px = tid + (i << 8);
    pvalid[i] = (px < 1156);
    int py = px / 34, pxx = px - py * 34;
    if (!pvalid[i]) { py = 0; pxx = 0; }
    ib[i] = py * 36 + pxx;
  }
  const int toff[9] = {0, 1, 2, 36, 37, 38, 72, 73, 74};

  for (int ocq = 0; ocq < 4; ocq++) {
    __half2 a2[5][8];
#pragma unroll
    for (int i = 0; i < 5; i++)
#pragma unroll
      for (int o = 0; o < 8; o++) a2[i][o] = __float2half2_rn(0.f);

    for (int tap = 0; tap < 9; tap++) {
      const __half2* wrow = (const __half2*)(wH + (tap * 32 + ocq * 8) * 32);
      int ia[5];
#pragma unroll
      for (int i = 0; i < 5; i++) ia[i] = (ib[i] + toff[tap]) * 36;
#pragma unroll
      for (int icq = 0; icq < 8; icq++) {
        __half2 iv[5][2];
#pragma unroll
        for (int i = 0; i < 5; i++) {
          const __half2* ip = (const __half2*)(inH + ia[i] + (icq << 2));
          iv[i][0] = ip[0]; iv[i][1] = ip[1];
        }
#pragma unroll
        for (int o = 0; o < 8; o++) {
          __half2 w0 = wrow[o * 16 + icq * 2];
          __half2 w1 = wrow[o * 16 + icq * 2 + 1];
#pragma unroll
          for (int i = 0; i < 5; i++) {
            a2[i][o] = __hfma2(iv[i][0], w0, a2[i][o]);
            a2[i][o] = __hfma2(iv[i][1], w1, a2[i][o]);
          }
        }
      }
    }
    // stats + normalize + relu + store
    float val[5][8], ps[8], pq[8];
#pragma unroll
    for (int o = 0; o < 8; o++) { ps[o] = 0.f; pq[o] = 0.f; }
#pragma unroll
    for (int i = 0; i < 5; i++)
#pragma unroll
      for (int o = 0; o < 8; o++) {
        float v = __low2float(a2[i][o]) + __high2float(a2[i][o]);
        val[i][o] = v;
        if (pvalid[i]) { ps[o] += v; pq[o] += v * v; }
      }
#pragma unroll
    for (int off = 32; off; off >>= 1)
#pragma unroll
      for (int o = 0; o < 8; o++) {
        ps[o] += __shfl_xor(ps[o], off);
        pq[o] += __shfl_xor(pq[o], off);
      }
    if ((tid & 63) == 0) {
      int wid = tid >> 6;
#pragma unroll
      for (int o = 0; o < 8; o++) { red[wid * 16 + o] = ps[o]; red[wid * 16 + 8 + o] = pq[o]; }
    }
    __syncthreads();
    float mean[8], sc[8], sh[8];
#pragma unroll
    for (int o = 0; o < 8; o++) {
      float fs = red[o] + red[16 + o] + red[32 + o] + red[48 + o];
      float fq = red[8 + o] + red[24 + o] + red[40 + o] + red[56 + o];
      float mu = fs * (1.f / 1156.f);
      float var = fq * (1.f / 1156.f) - mu * mu;
      mean[o] = mu;
      sc[o] = rsqrtf(var + 1e-5f) * gb[ocq * 8 + o];
      sh[o] = gb[32 + ocq * 8 + o];
    }
#pragma unroll
    for (int i = 0; i < 5; i++) {
      if (!pvalid[i]) continue;
      int px = tid + (i << 8);
      unsigned uu[4];
#pragma unroll
      for (int oq = 0; oq < 4; oq++) {
        unsigned short lo = __half_as_ushort(__float2half(fmaxf((val[i][oq * 2] - mean[oq * 2]) * sc[oq * 2] + sh[oq * 2], 0.f)));
        unsigned short hi = __half_as_ushort(__float2half(fmaxf((val[i][oq * 2 + 1] - mean[oq * 2 + 1]) * sc[oq * 2 + 1] + sh[oq * 2 + 1], 0.f)));
        uu[oq] = (unsigned)lo | ((unsigned)hi << 16);
      }
      uint4 st; st.x = uu[0]; st.y = uu[1]; st.z = uu[2]; st.w = uu[3];
      *(uint4*)(y1 + ((size_t)p * 1156 + px) * 32 + ocq * 8) = st;
    }
    __syncthreads();
  }
}

// ---------------- conv2 3x3 (32->8ch, 34^2 -> 32^2) + instancenorm + sigmoid --
__global__ __launch_bounds__(256) void conv2_kernel(
    const __half* __restrict__ y1, const float* __restrict__ c2w,
    const float* __restrict__ g2, const float* __restrict__ b2,
    float* __restrict__ wout)
{
  extern __shared__ __align__(16) char smem[];
  __half* inH = (__half*)smem;                        // [1156][36]
  __half* wH  = (__half*)(smem + 1156 * 36 * 2);      // [9][8][32]
  float* gb   = (float*)(smem + 1156 * 36 * 2 + 2304 * 2); // 16
  float* red  = gb + 16;                              // 64
  const int tid = threadIdx.x;
  const int p = blockIdx.x;

  const __half* src = y1 + (size_t)p * 36992;
  // 1156 pixels x 32 halves, uint2 (4 halves) per transaction -> 1156*8 = 9248
  for (int t = tid; t < 9248; t += 256) {
    int pix = t >> 3, icq = (t & 7) << 2;
    uint2 v = *(const uint2*)(src + pix * 32 + icq);
    *(uint2*)(inH + pix * 36 + icq) = v;
  }
  for (int t = tid; t < 2304; t += 256) {
    int oc = t / 288, rem = t - oc * 288;
    int ic = rem / 9, tap = rem - ic * 9;
    wH[(tap * 8 + oc) * 32 + ic] = __float2half(c2w[t]);
  }
  if (tid < 8) { gb[tid] = g2[tid]; gb[8 + tid] = b2[tid]; }
  __syncthreads();

  int ib[4];
#pragma unroll
  for (int i = 0; i < 4; i++) {
    int px = tid + (i << 8);
    ib[i] = (px >> 5) * 34 + (px & 31);
  }
  const int toff[9] = {0, 1, 2, 34, 35, 36, 68, 69, 70};

  __half2 a2[4][8];
#pragma unroll
  for (int i = 0; i < 4; i++)
#pragma unroll
    for (int o = 0; o < 8; o++) a2[i][o] = __float2half2_rn(0.f);

  for (int tap = 0; tap < 9; tap++) {
    const __half2* wrow = (const __half2*)(wH + (tap * 8) * 32);
    int ia[4];
#pragma unroll
    for (int i = 0; i < 4; i++) ia[i] = (ib[i] + toff[tap]) * 36;
#pragma unroll
    for (int icq = 0; icq < 8; icq++) {
      __half2 iv[4][2];
#pragma unroll
      for (int i = 0; i < 4; i++) {
        const __half2* ip = (const __half2*)(inH + ia[i] + (icq << 2));
        iv[i][0] = ip[0]; iv[i][1] = ip[1];
      }
#pragma unroll
      for (int o = 0; o < 8; o++) {
        __half2 w0 = wrow[o * 16 + icq * 2];
        __half2 w1 = wrow[o * 16 + icq * 2 + 1];
#pragma unroll
        for (int i = 0; i < 4; i++) {
          a2[i][o] = __hfma2(iv[i][0], w0, a2[i][o]);
          a2[i][o] = __hfma2(iv[i][1], w1, a2[i][o]);
        }
      }
    }
  }
  float val[4][8], ps[8], pq[8];
#pragma unroll
  for (int o = 0; o < 8; o++) { ps[o] = 0.f; pq[o] = 0.f; }
#pragma unroll
  for (int i = 0; i < 4; i++)
#pragma unroll
    for (int o = 0; o < 8; o++) {
      float v = __low2float(a2[i][o]) + __high2float(a2[i][o]);
      val[i][o] = v; ps[o] += v; pq[o] += v * v;
    }
#pragma unroll
  for (int off = 32; off; off >>= 1)
#pragma unroll
    for (int o = 0; o < 8; o++) {
      ps[o] += __shfl_xor(ps[o], off);
      pq[o] += __shfl_xor(pq[o], off);
    }
  if ((tid & 63) == 0) {
    int wid = tid >> 6;
#pragma unroll
    for (int o = 0; o < 8; o++) { red[wid * 16 + o] = ps[o]; red[wid * 16 + 8 + o] = pq[o]; }
  }
  __syncthreads();
#pragma unroll
  for (int o = 0; o < 8; o++) {
    float fs = red[o] + red[16 + o] + red[32 + o] + red[48 + o];
    float fq = red[8 + o] + red[24 + o] + red[40 + o] + red[56 + o];
    float mu = fs * (1.f / 1024.f);
    float var = fq * (1.f / 1024.f) - mu * mu;
    float sc = rsqrtf(var + 1e-5f) * gb[o];
    float sh = gb[8 + o];
#pragma unroll
    for (int i = 0; i < 4; i++) {
      int px = tid + (i << 8);
      float xv = (val[i][o] - mu) * sc + sh;
      float sig = 1.f / (1.f + __expf(-xv));
      wout[((size_t)o << 20) + ((size_t)p << 10) + px] = sig;
    }
  }
}

// ---------------- fused attention, bf16 MFMA 16x16x32 -------------------------
// block: 64 q-rows of one (b,h); 4 waves x 16 rows. K/V tiles of 64 staged in LDS.
__global__ __launch_bounds__(256) void attn_kernel(
    const unsigned short* __restrict__ qkv,  // bf16 bits [8192][1536]
    const float* __restrict__ wppe,          // [8][1024][1024]
    float* __restrict__ oh)                  // [8192][512] = (b,n,h,d)
{
  __shared__ __align__(16) unsigned short k_lds[64 * 72];
  __shared__ __align__(16) unsigned short v_lds[64 * 72]; // transposed [d][m ^ swz]
  __shared__ __align__(16) unsigned short p_lds[4 * 16 * 72];
  const int tid = threadIdx.x;
  const int wv = tid >> 6, ln = tid & 63;
  const int lr = ln & 15, lq = ln >> 4;
  const int b = blockIdx.y >> 3, h = blockIdx.y & 7;
  const int n0 = blockIdx.x << 6;

  const size_t qoff = (size_t)((b << 10) + n0 + (wv << 4) + lr) * 1536 + (h << 6);
  bf16x8 qf0 = *(const bf16x8*)(qkv + qoff + lq * 8);
  bf16x8 qf1 = *(const bf16x8*)(qkv + qoff + 32 + lq * 8);

  f32x4 acc[4];
#pragma unroll
  for (int dt = 0; dt < 4; dt++) acc[dt] = (f32x4){0.f, 0.f, 0.f, 0.f};
  float den[4] = {0.f, 0.f, 0.f, 0.f};
  const float* wp = wppe + ((size_t)h << 20);

  for (int m0 = 0; m0 < 1024; m0 += 64) {
    __syncthreads();
    for (int t = tid; t < 512; t += 256) {
      int m = t >> 3, dq = t & 7;
      const unsigned short* kr = qkv + (size_t)((b << 10) + m0 + m) * 1536 + 512 + (h << 6) + dq * 8;
      *(uint4*)&k_lds[m * 72 + dq * 8] = *(const uint4*)kr;
      uint4 vvv = *(const uint4*)(kr + 512);
      unsigned short tmp[8];
      *(uint4*)tmp = vvv;
#pragma unroll
      for (int i = 0; i < 8; i++) {
        int d = dq * 8 + i;
        v_lds[d * 72 + (m ^ (((d >> 3) & 7) << 3))] = tmp[i];
      }
    }
    __syncthreads();

    f32x4 s[4];
#pragma unroll
    for (int mt = 0; mt < 4; mt++) {
      const unsigned short* kb = &k_lds[(mt * 16 + lr) * 72 + lq * 8];
      f32x4 cz = (f32x4){0.f, 0.f, 0.f, 0.f};
      cz = __builtin_amdgcn_mfma_f32_16x16x32_bf16(qf0, *(const bf16x8*)kb, cz, 0, 0, 0);
      cz = __builtin_amdgcn_mfma_f32_16x16x32_bf16(qf1, *(const bf16x8*)(kb + 32), cz, 0, 0, 0);
      s[mt] = cz;
    }
#pragma unroll
    for (int mt = 0; mt < 4; mt++)
#pragma unroll
      for (int reg = 0; reg < 4; reg++) {
        int rrow = lq * 4 + reg;
        float wvl = wp[(size_t)(n0 + (wv << 4) + rrow) * 1024 + (m0 + mt * 16 + lr)];
        float pv = wvl * __expf(s[mt][reg] * 0.125f);
        den[reg] += pv;
        p_lds[((wv << 4) + rrow) * 72 + mt * 16 + lr] = f2bf(pv);
      }
    const unsigned short* pb = &p_lds[((wv << 4) + lr) * 72];
    bf16x8 pa0 = *(const bf16x8*)(pb + lq * 8);
    bf16x8 pa1 = *(const bf16x8*)(pb + 32 + lq * 8);
#pragma unroll
    for (int dt = 0; dt < 4; dt++) {
      int d = dt * 16 + lr;
      int sw = ((d >> 3) & 7) << 3;
      const unsigned short* vb = &v_lds[d * 72];
      acc[dt] = __builtin_amdgcn_mfma_f32_16x16x32_bf16(pa0, *(const bf16x8*)(vb + ((lq * 8) ^ sw)), acc[dt], 0, 0, 0);
      acc[dt] = __builtin_amdgcn_mfma_f32_16x16x32_bf16(pa1, *(const bf16x8*)(vb + ((32 + lq * 8) ^ sw)), acc[dt], 0, 0, 0);
    }
  }
#pragma unroll
  for (int off = 1; off < 16; off <<= 1)
#pragma unroll
    for (int reg = 0; reg < 4; reg++) den[reg] += __shfl_xor(den[reg], off);
#pragma unroll
  for (int dt = 0; dt < 4; dt++)
#pragma unroll
    for (int reg = 0; reg < 4; reg++) {
      size_t row = (size_t)((b << 10) + n0 + (wv << 4) + lq * 4 + reg);
      oh[row * 512 + (h << 6) + dt * 16 + lr] = acc[dt][reg] / den[reg];
    }
}

// ---------------------------------------------------------------------------
extern "C" void kernel_launch(void* const* d_in, const int* in_sizes, int n_in,
                              void* d_out, int out_size, void* d_ws, size_t ws_size,
                              hipStream_t stream) {
  (void)in_sizes; (void)n_in; (void)out_size; (void)ws_size;
  const float* x     = (const float*)d_in[0];
  const float* rpe   = (const float*)d_in[1];
  const float* wqkv  = (const float*)d_in[2];
  const float* wproj = (const float*)d_in[3];
  const float* bproj = (const float*)d_in[4];
  const float* c1w   = (const float*)d_in[5];
  // d_in[6] = c1b: cancels exactly in the following instance-norm (mean-subtracted)
  const float* g1w   = (const float*)d_in[7];
  const float* g1b   = (const float*)d_in[8];
  const float* c2w   = (const float*)d_in[9];
  // d_in[10] = c2b: cancels likewise
  const float* g2w   = (const float*)d_in[11];
  const float* g2b   = (const float*)d_in[12];
  float* out = (float*)d_out;

  char* ws = (char*)d_ws;
  unsigned short* qkv_bf = (unsigned short*)ws;            // 25,165,824 B
  float* wppe = (float*)(ws + 25165824);                   // 33,554,432 B
  __half* y1  = (__half*)(ws + 58720256);                  // 75,759,616 B
  float* ohb  = (float*)(ws + 58720256);                   // overlaps y1 (y1 dead)

  // 1) qkv = x @ wqkv^T  -> bf16
  gemm_bt<true><<<dim3(12, 64), 256, 0, stream>>>(x, wqkv, qkv_bf, nullptr, 8192, 1536, 512);

  // 2) conv1 + IN + relu
  const int lds1 = 1296 * 36 * 2 + 9216 * 2 + 64 * 4 + 64 * 4; // 112,256
  hipFuncSetAttribute(reinterpret_cast<const void*>(&conv1_kernel),
                      hipFuncAttributeMaxDynamicSharedMemorySize, lds1);
  conv1_kernel<<<1024, 256, lds1, stream>>>(rpe, c1w, g1w, g1b, y1);

  // 3) conv2 + IN + sigmoid -> w
  const int lds2 = 1156 * 36 * 2 + 2304 * 2 + 16 * 4 + 64 * 4; // 88,160
  hipFuncSetAttribute(reinterpret_cast<const void*>(&conv2_kernel),
                      hipFuncAttributeMaxDynamicSharedMemorySize, lds2);
  conv2_kernel<<<1024, 256, lds2, stream>>>(y1, c2w, g2w, g2b, wppe);

  // 4) fused attention
  attn_kernel<<<dim3(16, 64), 256, 0, stream>>>(qkv_bf, wppe, ohb);

  // 5) out = oh @ wproj^T + bproj
  gemm_bt<false><<<dim3(4, 64), 256, 0, stream>>>(ohb, wproj, out, bproj, 8192, 512, 512);
}

// Round 3
// 472.824 us; speedup vs baseline: 1.7789x; 1.7789x over previous
//
#include <hip/hip_runtime.h>
#include <hip/hip_fp16.h>

// MPA_16698832847132 — round 2: replace half2-VALU convs with fused f16-MFMA
// implicit-GEMM conv kernel (conv1+IN+relu+conv2+IN+sigmoid in one block/image).
// Pipeline: [gemm_bt f32->bf16 qkv] [conv_fused] [attn bf16-MFMA] [gemm_bt f32 proj]
// Workspace: qkv bf16 @0 (25,165,824) | w f32 @25,165,824 (33,554,432) | oh f32 @58,720,256 (16,777,216)

typedef __attribute__((ext_vector_type(8))) short bf16x8;
typedef __attribute__((ext_vector_type(8))) _Float16 f16x8;
typedef __attribute__((ext_vector_type(4))) float f32x4;

__device__ __forceinline__ unsigned short f2bf(float f) {
  unsigned u = __builtin_bit_cast(unsigned, f);
  u += 0x7FFFu + ((u >> 16) & 1u);
  return (unsigned short)(u >> 16);
}

// ---------------- C[M][N] = A[M][K] * B[N][K]^T (+bias); 128x128 tile, BK=8 ----
template<bool OUT_BF16>
__global__ __launch_bounds__(256) void gemm_bt(
    const float* __restrict__ A, const float* __restrict__ B,
    void* __restrict__ Cv, const float* __restrict__ bias,
    int M, int N, int K)
{
  __shared__ __align__(16) float As[8][132];
  __shared__ __align__(16) float Bs[8][132];
  const int tid = threadIdx.x;
  const int m0 = blockIdx.y * 128, n0 = blockIdx.x * 128;
  const int ty = tid >> 4, tx = tid & 15;
  float acc[2][2][4][4];
#pragma unroll
  for (int a = 0; a < 2; a++)
#pragma unroll
    for (int b = 0; b < 2; b++)
#pragma unroll
      for (int i = 0; i < 4; i++)
#pragma unroll
        for (int j = 0; j < 4; j++) acc[a][b][i][j] = 0.f;

  const int r = tid >> 1, kq = (tid & 1) * 4;
  const float* Ap = A + (size_t)(m0 + r) * K + kq;
  const float* Bp = B + (size_t)(n0 + r) * K + kq;

  for (int k0 = 0; k0 < K; k0 += 8) {
    float4 av = *(const float4*)(Ap + k0);
    float4 bv = *(const float4*)(Bp + k0);
    __syncthreads();
    As[kq + 0][r] = av.x; As[kq + 1][r] = av.y; As[kq + 2][r] = av.z; As[kq + 3][r] = av.w;
    Bs[kq + 0][r] = bv.x; Bs[kq + 1][r] = bv.y; Bs[kq + 2][r] = bv.z; Bs[kq + 3][r] = bv.w;
    __syncthreads();
#pragma unroll
    for (int kk = 0; kk < 8; kk++) {
      float4 a0 = *(const float4*)&As[kk][ty * 4];
      float4 a1 = *(const float4*)&As[kk][64 + ty * 4];
      float4 b0 = *(const float4*)&Bs[kk][tx * 4];
      float4 b1 = *(const float4*)&Bs[kk][64 + tx * 4];
      float ar[2][4] = {{a0.x, a0.y, a0.z, a0.w}, {a1.x, a1.y, a1.z, a1.w}};
      float br[2][4] = {{b0.x, b0.y, b0.z, b0.w}, {b1.x, b1.y, b1.z, b1.w}};
#pragma unroll
      for (int rh = 0; rh < 2; rh++)
#pragma unroll
        for (int i = 0; i < 4; i++)
#pragma unroll
          for (int ch = 0; ch < 2; ch++)
#pragma unroll
            for (int j = 0; j < 4; j++)
              acc[rh][ch][i][j] = fmaf(ar[rh][i], br[ch][j], acc[rh][ch][i][j]);
    }
  }

#pragma unroll
  for (int rh = 0; rh < 2; rh++)
#pragma unroll
    for (int i = 0; i < 4; i++) {
      const int row = m0 + rh * 64 + ty * 4 + i;
#pragma unroll
      for (int ch = 0; ch < 2; ch++) {
        const int col = n0 + ch * 64 + tx * 4;
        float v0 = acc[rh][ch][i][0], v1 = acc[rh][ch][i][1];
        float v2 = acc[rh][ch][i][2], v3 = acc[rh][ch][i][3];
        if (bias) { v0 += bias[col]; v1 += bias[col + 1]; v2 += bias[col + 2]; v3 += bias[col + 3]; }
        if (OUT_BF16) {
          unsigned long long u = (unsigned long long)f2bf(v0)
                               | ((unsigned long long)f2bf(v1) << 16)
                               | ((unsigned long long)f2bf(v2) << 32)
                               | ((unsigned long long)f2bf(v3) << 48);
          *(unsigned long long*)((unsigned short*)Cv + (size_t)row * N + col) = u;
        } else {
          float4 o; o.x = v0; o.y = v1; o.z = v2; o.w = v3;
          *(float4*)((float*)Cv + (size_t)row * N + col) = o;
        }
      }
    }
}

// ---------------- fused conv1+IN+relu+conv2+IN+sigmoid, f16 MFMA ---------------
// One image per block (grid 1024), 256 threads = 4 waves.
// LDS: inA half[1296][32] @0 (82,944) | yB half[1156][32] @82,944 (73,984)
//      statL f32[256] @156,928 | aL/cL f32[32+32] @157,952 -> total 158,208
// Phase 2 overlays transF f32[8][1032] on inA.
__global__ __launch_bounds__(256, 1) void conv_fused(
    const float* __restrict__ rpe,
    const float* __restrict__ c1w, const float* __restrict__ g1, const float* __restrict__ b1,
    const float* __restrict__ c2w, const float* __restrict__ g2, const float* __restrict__ b2,
    float* __restrict__ wout)
{
  extern __shared__ __align__(16) char smem[];
  unsigned short* inA = (unsigned short*)smem;
  unsigned short* yB  = (unsigned short*)(smem + 82944);
  float* statL = (float*)(smem + 156928);   // 256 f32
  float* aL    = (float*)(smem + 157952);   // 32
  float* cL    = aL + 32;                   // 32
  float* transF = (float*)smem;             // phase-2 overlay [8][1032]

  const int tid = threadIdx.x;
  const int wv = tid >> 6, ln = tid & 63;
  const int lr = ln & 15, lq = ln >> 4;
  const int p = blockIdx.x;

  // ---- stage input: rpe crop row -> LDS f16, channel-inner [1296][32]
  const float* src = rpe + (size_t)(((p >> 5) + 2) * 36 + (p & 31) + 2) * 41472;
  for (int t = tid; t < 10368; t += 256) {
    int pix = t >> 3, dq = (t & 7) << 2;
    float4 v = *(const float4*)(src + pix * 32 + dq);
    __half2 h0 = __floats2half2_rn(v.x, v.y);
    __half2 h1 = __floats2half2_rn(v.z, v.w);
    uint2 u; u.x = __builtin_bit_cast(unsigned, h0); u.y = __builtin_bit_cast(unsigned, h1);
    *(uint2*)(inA + pix * 32 + dq) = u;
  }

  // ---- w1 fragments straight to registers (B-frag: col=lr -> oc, k=lq*8+j -> ic)
  f16x8 w1f[2][9];
  const int ic0 = lq * 8;
#pragma unroll
  for (int ct = 0; ct < 2; ct++) {
    int oc = ct * 16 + lr;
#pragma unroll
    for (int tap = 0; tap < 9; tap++) {
      f16x8 f;
#pragma unroll
      for (int j = 0; j < 8; j++)
        f[j] = (_Float16)c1w[((oc * 32 + ic0 + j) * 3 + tap / 3) * 3 + tap % 3];
      w1f[ct][tap] = f;
    }
  }
  __syncthreads();

  // ---- conv1: 73 row-tiles of 16 out-pixels, K=288 (9 taps x 32ic), N=32 (2 col-tiles)
  constexpr int OFF1[9] = {0, 32, 64, 1152, 1184, 1216, 2304, 2336, 2368};
  float s0 = 0.f, q0 = 0.f, s1 = 0.f, q1 = 0.f;
  for (int t = wv; t < 73; t += 4) {
    int m = t * 16 + lr;
    int ms = m < 1155 ? m : 1155;
    const unsigned short* ab = inA + ((ms / 34) * 36 + (ms % 34)) * 32 + lq * 8;
    f32x4 c0 = {0.f, 0.f, 0.f, 0.f}, c1v = {0.f, 0.f, 0.f, 0.f};
#pragma unroll
    for (int tap = 0; tap < 9; tap++) {
      f16x8 av = *(const f16x8*)(ab + OFF1[tap]);
      c0  = __builtin_amdgcn_mfma_f32_16x16x32_f16(av, w1f[0][tap], c0, 0, 0, 0);
      c1v = __builtin_amdgcn_mfma_f32_16x16x32_f16(av, w1f[1][tap], c1v, 0, 0, 0);
    }
#pragma unroll
    for (int r = 0; r < 4; r++) {
      int mo = t * 16 + lq * 4 + r;
      if (mo < 1156) {
        float v0 = c0[r], v1 = c1v[r];
        yB[mo * 32 + lr]      = __half_as_ushort(__float2half(v0));
        yB[mo * 32 + 16 + lr] = __half_as_ushort(__float2half(v1));
        s0 += v0; q0 += v0 * v0; s1 += v1; q1 += v1 * v1;
      }
    }
  }
  // stats reduce: lanes sharing lr (xor 16, 32)
#pragma unroll
  for (int off = 16; off < 64; off <<= 1) {
    s0 += __shfl_xor(s0, off); q0 += __shfl_xor(q0, off);
    s1 += __shfl_xor(s1, off); q1 += __shfl_xor(q1, off);
  }
  if (ln < 16) {
    float* st = statL + wv * 64;
    st[ln] = s0; st[16 + ln] = q0; st[32 + ln] = s1; st[48 + ln] = q1;
  }
  __syncthreads();
  if (tid < 32) {
    int cti = tid >> 4, lri = tid & 15;
    float s = 0.f, q = 0.f;
#pragma unroll
    for (int w = 0; w < 4; w++) {
      s += statL[w * 64 + cti * 32 + lri];
      q += statL[w * 64 + cti * 32 + 16 + lri];
    }
    float mu = s * (1.f / 1156.f);
    float var = q * (1.f / 1156.f) - mu * mu;
    float a_ = rsqrtf(var + 1e-5f) * g1[tid];
    aL[tid] = a_; cL[tid] = b1[tid] - mu * a_;
  }
  // ---- w2 fragments (overlap with stats barrier region; independent global loads)
  f16x8 w2f[9];
#pragma unroll
  for (int tap = 0; tap < 9; tap++) {
    f16x8 f;
    if (lr < 8) {
#pragma unroll
      for (int j = 0; j < 8; j++)
        f[j] = (_Float16)c2w[((lr * 32 + ic0 + j) * 3 + tap / 3) * 3 + tap % 3];
    } else {
#pragma unroll
      for (int j = 0; j < 8; j++) f[j] = (_Float16)0.f;
    }
    w2f[tap] = f;
  }
  __syncthreads();

  // ---- normalize + relu, in-place RMW on yB
  for (int i = tid * 8; i < 36992; i += 2048) {
    f16x8 raw = *(const f16x8*)(yB + i);
    int ocb = i & 31;
    f16x8 outv;
#pragma unroll
    for (int e = 0; e < 8; e++) {
      float v = (float)raw[e];
      v = fmaxf(v * aL[ocb + e] + cL[ocb + e], 0.f);
      outv[e] = (_Float16)v;
    }
    *(f16x8*)(yB + i) = outv;
  }
  __syncthreads();

  // ---- conv2: 64 row-tiles, K=288, N=8 (cols 8..15 zero)
  constexpr int OFF2[9] = {0, 32, 64, 1088, 1120, 1152, 2176, 2208, 2240};
  float s2 = 0.f, q2 = 0.f;
  for (int t = wv; t < 64; t += 4) {
    int m = t * 16 + lr;
    const unsigned short* ab = yB + ((m >> 5) * 34 + (m & 31)) * 32 + lq * 8;
    f32x4 cc = {0.f, 0.f, 0.f, 0.f};
#pragma unroll
    for (int tap = 0; tap < 9; tap++) {
      f16x8 av = *(const f16x8*)(ab + OFF2[tap]);
      cc = __builtin_amdgcn_mfma_f32_16x16x32_f16(av, w2f[tap], cc, 0, 0, 0);
    }
#pragma unroll
    for (int r = 0; r < 4; r++) {
      int mo = t * 16 + lq * 4 + r;
      float v = cc[r];
      s2 += v; q2 += v * v;
      if (lr < 8) transF[lr * 1032 + mo] = v;
    }
  }
#pragma unroll
  for (int off = 16; off < 64; off <<= 1) {
    s2 += __shfl_xor(s2, off); q2 += __shfl_xor(q2, off);
  }
  if (ln < 16) { statL[wv * 32 + ln] = s2; statL[wv * 32 + 16 + ln] = q2; }
  __syncthreads();
  if (tid < 8) {
    float s = 0.f, q = 0.f;
#pragma unroll
    for (int w = 0; w < 4; w++) { s += statL[w * 32 + tid]; q += statL[w * 32 + 16 + tid]; }
    float mu = s * (1.f / 1024.f);
    float var = q * (1.f / 1024.f) - mu * mu;
    float a_ = rsqrtf(var + 1e-5f) * g2[tid];
    aL[tid] = a_; cL[tid] = b2[tid] - mu * a_;
  }
  __syncthreads();

  // ---- sigmoid + coalesced store: wout[oc][p][pix]
  for (int idx = tid; idx < 2048; idx += 256) {
    int oc = idx >> 8, p4 = (idx & 255) << 2;
    float4 v = *(const float4*)&transF[oc * 1032 + p4];
    float a_ = aL[oc], c_ = cL[oc];
    float4 o;
    o.x = 1.f / (1.f + __expf(-(v.x * a_ + c_)));
    o.y = 1.f / (1.f + __expf(-(v.y * a_ + c_)));
    o.z = 1.f / (1.f + __expf(-(v.z * a_ + c_)));
    o.w = 1.f / (1.f + __expf(-(v.w * a_ + c_)));
    *(float4*)(wout + ((size_t)oc << 20) + ((size_t)p << 10) + p4) = o;
  }
}

// ---------------- fused attention, bf16 MFMA 16x16x32 -------------------------
__global__ __launch_bounds__(256) void attn_kernel(
    const unsigned short* __restrict__ qkv,  // bf16 bits [8192][1536]
    const float* __restrict__ wppe,          // [8][1024][1024]
    float* __restrict__ oh)                  // [8192][512] = (b,n,h,d)
{
  __shared__ __align__(16) unsigned short k_lds[64 * 72];
  __shared__ __align__(16) unsigned short v_lds[64 * 72]; // transposed [d][m ^ swz]
  __shared__ __align__(16) unsigned short p_lds[4 * 16 * 72];
  const int tid = threadIdx.x;
  const int wv = tid >> 6, ln = tid & 63;
  const int lr = ln & 15, lq = ln >> 4;
  const int b = blockIdx.y >> 3, h = blockIdx.y & 7;
  const int n0 = blockIdx.x << 6;

  const size_t qoff = (size_t)((b << 10) + n0 + (wv << 4) + lr) * 1536 + (h << 6);
  bf16x8 qf0 = *(const bf16x8*)(qkv + qoff + lq * 8);
  bf16x8 qf1 = *(const bf16x8*)(qkv + qoff + 32 + lq * 8);

  f32x4 acc[4];
#pragma unroll
  for (int dt = 0; dt < 4; dt++) acc[dt] = (f32x4){0.f, 0.f, 0.f, 0.f};
  float den[4] = {0.f, 0.f, 0.f, 0.f};
  const float* wp = wppe + ((size_t)h << 20);

  for (int m0 = 0; m0 < 1024; m0 += 64) {
    __syncthreads();
    for (int t = tid; t < 512; t += 256) {
      int m = t >> 3, dq = t & 7;
      const unsigned short* kr = qkv + (size_t)((b << 10) + m0 + m) * 1536 + 512 + (h << 6) + dq * 8;
      *(uint4*)&k_lds[m * 72 + dq * 8] = *(const uint4*)kr;
      uint4 vvv = *(const uint4*)(kr + 512);
      unsigned short tmp[8];
      *(uint4*)tmp = vvv;
#pragma unroll
      for (int i = 0; i < 8; i++) {
        int d = dq * 8 + i;
        v_lds[d * 72 + (m ^ (((d >> 3) & 7) << 3))] = tmp[i];
      }
    }
    __syncthreads();

    f32x4 s[4];
#pragma unroll
    for (int mt = 0; mt < 4; mt++) {
      const unsigned short* kb = &k_lds[(mt * 16 + lr) * 72 + lq * 8];
      f32x4 cz = (f32x4){0.f, 0.f, 0.f, 0.f};
      cz = __builtin_amdgcn_mfma_f32_16x16x32_bf16(qf0, *(const bf16x8*)kb, cz, 0, 0, 0);
      cz = __builtin_amdgcn_mfma_f32_16x16x32_bf16(qf1, *(const bf16x8*)(kb + 32), cz, 0, 0, 0);
      s[mt] = cz;
    }
#pragma unroll
    for (int mt = 0; mt < 4; mt++)
#pragma unroll
      for (int reg = 0; reg < 4; reg++) {
        int rrow = lq * 4 + reg;
        float wvl = wp[(size_t)(n0 + (wv << 4) + rrow) * 1024 + (m0 + mt * 16 + lr)];
        float pv = wvl * __expf(s[mt][reg] * 0.125f);
        den[reg] += pv;
        p_lds[((wv << 4) + rrow) * 72 + mt * 16 + lr] = f2bf(pv);
      }
    const unsigned short* pb = &p_lds[((wv << 4) + lr) * 72];
    bf16x8 pa0 = *(const bf16x8*)(pb + lq * 8);
    bf16x8 pa1 = *(const bf16x8*)(pb + 32 + lq * 8);
#pragma unroll
    for (int dt = 0; dt < 4; dt++) {
      int d = dt * 16 + lr;
      int sw = ((d >> 3) & 7) << 3;
      const unsigned short* vb = &v_lds[d * 72];
      acc[dt] = __builtin_amdgcn_mfma_f32_16x16x32_bf16(pa0, *(const bf16x8*)(vb + ((lq * 8) ^ sw)), acc[dt], 0, 0, 0);
      acc[dt] = __builtin_amdgcn_mfma_f32_16x16x32_bf16(pa1, *(const bf16x8*)(vb + ((32 + lq * 8) ^ sw)), acc[dt], 0, 0, 0);
    }
  }
#pragma unroll
  for (int off = 1; off < 16; off <<= 1)
#pragma unroll
    for (int reg = 0; reg < 4; reg++) den[reg] += __shfl_xor(den[reg], off);
#pragma unroll
  for (int dt = 0; dt < 4; dt++)
#pragma unroll
    for (int reg = 0; reg < 4; reg++) {
      size_t row = (size_t)((b << 10) + n0 + (wv << 4) + lq * 4 + reg);
      oh[row * 512 + (h << 6) + dt * 16 + lr] = acc[dt][reg] / den[reg];
    }
}

// ---------------------------------------------------------------------------
extern "C" void kernel_launch(void* const* d_in, const int* in_sizes, int n_in,
                              void* d_out, int out_size, void* d_ws, size_t ws_size,
                              hipStream_t stream) {
  (void)in_sizes; (void)n_in; (void)out_size; (void)ws_size;
  const float* x     = (const float*)d_in[0];
  const float* rpe   = (const float*)d_in[1];
  const float* wqkv  = (const float*)d_in[2];
  const float* wproj = (const float*)d_in[3];
  const float* bproj = (const float*)d_in[4];
  const float* c1w   = (const float*)d_in[5];
  // d_in[6] = c1b: cancels exactly in the following instance-norm
  const float* g1w   = (const float*)d_in[7];
  const float* g1b   = (const float*)d_in[8];
  const float* c2w   = (const float*)d_in[9];
  // d_in[10] = c2b: cancels likewise
  const float* g2w   = (const float*)d_in[11];
  const float* g2b   = (const float*)d_in[12];
  float* out = (float*)d_out;

  char* ws = (char*)d_ws;
  unsigned short* qkv_bf = (unsigned short*)ws;            // 25,165,824 B
  float* wppe = (float*)(ws + 25165824);                   // 33,554,432 B
  float* ohb  = (float*)(ws + 58720256);                   // 16,777,216 B

  // 1) qkv = x @ wqkv^T  -> bf16
  gemm_bt<true><<<dim3(12, 64), 256, 0, stream>>>(x, wqkv, qkv_bf, nullptr, 8192, 1536, 512);

  // 2) fused conv1+IN+relu+conv2+IN+sigmoid -> w
  const int ldsC = 158208;
  hipFuncSetAttribute(reinterpret_cast<const void*>(&conv_fused),
                      hipFuncAttributeMaxDynamicSharedMemorySize, ldsC);
  conv_fused<<<1024, 256, ldsC, stream>>>(rpe, c1w, g1w, g1b, c2w, g2w, g2b, wppe);

  // 3) fused attention
  attn_kernel<<<dim3(16, 64), 256, 0, stream>>>(qkv_bf, wppe, ohb);

  // 4) out = oh @ wproj^T + bproj
  gemm_bt<false><<<dim3(4, 64), 256, 0, stream>>>(ohb, wproj, out, bproj, 8192, 512, 512);
}

// Round 4
// 268.867 us; speedup vs baseline: 3.1284x; 1.7586x over previous
//
#include <hip/hip_runtime.h>
#include <hip/hip_fp16.h>

// MPA_16698832847132 — round 3:
//  (a) conv_fused 256->512 threads (2 waves/SIMD, latency hiding)
//  (b) qkv/proj GEMMs: SIMT f32 -> f16 MFMA 16x16x32 (128x128x32 tile)
// Workspace: qkv bf16 @0 (25,165,824) | w f32 @25,165,824 (33,554,432) | oh f32 @58,720,256 (16,777,216)

typedef __attribute__((ext_vector_type(8))) short bf16x8;
typedef __attribute__((ext_vector_type(8))) _Float16 f16x8;
typedef __attribute__((ext_vector_type(4))) float f32x4;

__device__ __forceinline__ unsigned short f2bf(float f) {
  unsigned u = __builtin_bit_cast(unsigned, f);
  u += 0x7FFFu + ((u >> 16) & 1u);
  return (unsigned short)(u >> 16);
}

// ---------------- C[M][N] = A[M][K] * B[N][K]^T (+bias), f16 MFMA --------------
// 128x128 tile, BK=32, 256 thr = 4 waves (2x2), per-wave 64x64 via 4x4 16x16 frags.
template<bool OUT_BF16>
__global__ __launch_bounds__(256) void gemm_f16_bt(
    const float* __restrict__ A, const float* __restrict__ B,
    void* __restrict__ Cv, const float* __restrict__ bias,
    int M, int N, int K)
{
  __shared__ __align__(16) _Float16 As[128 * 40];
  __shared__ __align__(16) _Float16 Bs[128 * 40];
  const int tid = threadIdx.x;
  const int wv = tid >> 6, ln = tid & 63, lr = ln & 15, lq = ln >> 4;
  const int wm = wv >> 1, wn = wv & 1;
  const int m0 = blockIdx.y * 128, n0 = blockIdx.x * 128;

  f32x4 acc[4][4];
#pragma unroll
  for (int i = 0; i < 4; i++)
#pragma unroll
    for (int j = 0; j < 4; j++) acc[i][j] = (f32x4){0.f, 0.f, 0.f, 0.f};

  const int sr = tid >> 1, sk = (tid & 1) * 16;
  const float* Ap = A + (size_t)(m0 + sr) * K + sk;
  const float* Bp = B + (size_t)(n0 + sr) * K + sk;

  for (int k0 = 0; k0 < K; k0 += 32) {
    float4 av0 = *(const float4*)(Ap + k0);
    float4 av1 = *(const float4*)(Ap + k0 + 4);
    float4 av2 = *(const float4*)(Ap + k0 + 8);
    float4 av3 = *(const float4*)(Ap + k0 + 12);
    float4 bv0 = *(const float4*)(Bp + k0);
    float4 bv1 = *(const float4*)(Bp + k0 + 4);
    float4 bv2 = *(const float4*)(Bp + k0 + 8);
    float4 bv3 = *(const float4*)(Bp + k0 + 12);
    __syncthreads();
    {
      f16x8 p0, p1, r0, r1;
      p0[0]=(_Float16)av0.x; p0[1]=(_Float16)av0.y; p0[2]=(_Float16)av0.z; p0[3]=(_Float16)av0.w;
      p0[4]=(_Float16)av1.x; p0[5]=(_Float16)av1.y; p0[6]=(_Float16)av1.z; p0[7]=(_Float16)av1.w;
      p1[0]=(_Float16)av2.x; p1[1]=(_Float16)av2.y; p1[2]=(_Float16)av2.z; p1[3]=(_Float16)av2.w;
      p1[4]=(_Float16)av3.x; p1[5]=(_Float16)av3.y; p1[6]=(_Float16)av3.z; p1[7]=(_Float16)av3.w;
      r0[0]=(_Float16)bv0.x; r0[1]=(_Float16)bv0.y; r0[2]=(_Float16)bv0.z; r0[3]=(_Float16)bv0.w;
      r0[4]=(_Float16)bv1.x; r0[5]=(_Float16)bv1.y; r0[6]=(_Float16)bv1.z; r0[7]=(_Float16)bv1.w;
      r1[0]=(_Float16)bv2.x; r1[1]=(_Float16)bv2.y; r1[2]=(_Float16)bv2.z; r1[3]=(_Float16)bv2.w;
      r1[4]=(_Float16)bv3.x; r1[5]=(_Float16)bv3.y; r1[6]=(_Float16)bv3.z; r1[7]=(_Float16)bv3.w;
      *(f16x8*)&As[sr * 40 + sk] = p0;
      *(f16x8*)&As[sr * 40 + sk + 8] = p1;
      *(f16x8*)&Bs[sr * 40 + sk] = r0;
      *(f16x8*)&Bs[sr * 40 + sk + 8] = r1;
    }
    __syncthreads();
    f16x8 af[4], bf[4];
#pragma unroll
    for (int mf = 0; mf < 4; mf++)
      af[mf] = *(const f16x8*)&As[(wm * 64 + mf * 16 + lr) * 40 + lq * 8];
#pragma unroll
    for (int nf = 0; nf < 4; nf++)
      bf[nf] = *(const f16x8*)&Bs[(wn * 64 + nf * 16 + lr) * 40 + lq * 8];
#pragma unroll
    for (int mf = 0; mf < 4; mf++)
#pragma unroll
      for (int nf = 0; nf < 4; nf++)
        acc[mf][nf] = __builtin_amdgcn_mfma_f32_16x16x32_f16(af[mf], bf[nf], acc[mf][nf], 0, 0, 0);
  }

#pragma unroll
  for (int mf = 0; mf < 4; mf++)
#pragma unroll
    for (int reg = 0; reg < 4; reg++) {
      const int row = m0 + wm * 64 + mf * 16 + lq * 4 + reg;
#pragma unroll
      for (int nf = 0; nf < 4; nf++) {
        const int col = n0 + wn * 64 + nf * 16 + lr;
        float v = acc[mf][nf][reg];
        if (bias) v += bias[col];
        if (OUT_BF16) ((unsigned short*)Cv)[(size_t)row * N + col] = f2bf(v);
        else          ((float*)Cv)[(size_t)row * N + col] = v;
      }
    }
}

// ---------------- fused conv1+IN+relu+conv2+IN+sigmoid, f16 MFMA ---------------
// One image per block (grid 1024), 512 threads = 8 waves (2/SIMD).
// LDS: inA half[1296][32] @0 (82,944) | yB half[1156][32] @82,944 (73,984)
//      statL f32[512] @156,928 | aL/cL f32[32+32] @158,976 -> total 159,232
// Phase 2 overlays transF f32[8][1032] on inA.
__global__ __launch_bounds__(512, 1) void conv_fused(
    const float* __restrict__ rpe,
    const float* __restrict__ c1w, const float* __restrict__ g1, const float* __restrict__ b1,
    const float* __restrict__ c2w, const float* __restrict__ g2, const float* __restrict__ b2,
    float* __restrict__ wout)
{
  extern __shared__ __align__(16) char smem[];
  unsigned short* inA = (unsigned short*)smem;
  unsigned short* yB  = (unsigned short*)(smem + 82944);
  float* statL = (float*)(smem + 156928);   // 512 f32
  float* aL    = (float*)(smem + 158976);   // 32
  float* cL    = aL + 32;                   // 32
  float* transF = (float*)smem;             // phase-2 overlay [8][1032]

  const int tid = threadIdx.x;
  const int wv = tid >> 6, ln = tid & 63;
  const int lr = ln & 15, lq = ln >> 4;
  const int p = blockIdx.x;

  // ---- stage input: rpe crop row -> LDS f16, channel-inner [1296][32]
  const float* src = rpe + (size_t)(((p >> 5) + 2) * 36 + (p & 31) + 2) * 41472;
  for (int t = tid; t < 10368; t += 512) {
    int pix = t >> 3, dq = (t & 7) << 2;
    float4 v = *(const float4*)(src + pix * 32 + dq);
    __half2 h0 = __floats2half2_rn(v.x, v.y);
    __half2 h1 = __floats2half2_rn(v.z, v.w);
    uint2 u; u.x = __builtin_bit_cast(unsigned, h0); u.y = __builtin_bit_cast(unsigned, h1);
    *(uint2*)(inA + pix * 32 + dq) = u;
  }

  // ---- w1 fragments straight to registers (B-frag: col=lr -> oc, k=lq*8+j -> ic)
  f16x8 w1f[2][9];
  const int ic0 = lq * 8;
#pragma unroll
  for (int ct = 0; ct < 2; ct++) {
    int oc = ct * 16 + lr;
#pragma unroll
    for (int tap = 0; tap < 9; tap++) {
      f16x8 f;
#pragma unroll
      for (int j = 0; j < 8; j++)
        f[j] = (_Float16)c1w[((oc * 32 + ic0 + j) * 3 + tap / 3) * 3 + tap % 3];
      w1f[ct][tap] = f;
    }
  }
  __syncthreads();

  // ---- conv1: 73 row-tiles of 16 out-pixels, K=288 (9 taps x 32ic), N=32
  constexpr int OFF1[9] = {0, 32, 64, 1152, 1184, 1216, 2304, 2336, 2368};
  float s0 = 0.f, q0 = 0.f, s1 = 0.f, q1 = 0.f;
  for (int t = wv; t < 73; t += 8) {
    int m = t * 16 + lr;
    int ms = m < 1155 ? m : 1155;
    const unsigned short* ab = inA + ((ms / 34) * 36 + (ms % 34)) * 32 + lq * 8;
    f32x4 c0 = {0.f, 0.f, 0.f, 0.f}, c1v = {0.f, 0.f, 0.f, 0.f};
#pragma unroll
    for (int tap = 0; tap < 9; tap++) {
      f16x8 av = *(const f16x8*)(ab + OFF1[tap]);
      c0  = __builtin_amdgcn_mfma_f32_16x16x32_f16(av, w1f[0][tap], c0, 0, 0, 0);
      c1v = __builtin_amdgcn_mfma_f32_16x16x32_f16(av, w1f[1][tap], c1v, 0, 0, 0);
    }
#pragma unroll
    for (int r = 0; r < 4; r++) {
      int mo = t * 16 + lq * 4 + r;
      if (mo < 1156) {
        float v0 = c0[r], v1 = c1v[r];
        yB[mo * 32 + lr]      = __half_as_ushort(__float2half(v0));
        yB[mo * 32 + 16 + lr] = __half_as_ushort(__float2half(v1));
        s0 += v0; q0 += v0 * v0; s1 += v1; q1 += v1 * v1;
      }
    }
  }
  // stats reduce: lanes sharing lr (xor 16, 32)
#pragma unroll
  for (int off = 16; off < 64; off <<= 1) {
    s0 += __shfl_xor(s0, off); q0 += __shfl_xor(q0, off);
    s1 += __shfl_xor(s1, off); q1 += __shfl_xor(q1, off);
  }
  if (ln < 16) {
    float* st = statL + wv * 64;
    st[ln] = s0; st[16 + ln] = q0; st[32 + ln] = s1; st[48 + ln] = q1;
  }
  __syncthreads();
  if (tid < 32) {
    int cti = tid >> 4, lri = tid & 15;
    float s = 0.f, q = 0.f;
#pragma unroll
    for (int w = 0; w < 8; w++) {
      s += statL[w * 64 + cti * 32 + lri];
      q += statL[w * 64 + cti * 32 + 16 + lri];
    }
    float mu = s * (1.f / 1156.f);
    float var = q * (1.f / 1156.f) - mu * mu;
    float a_ = rsqrtf(var + 1e-5f) * g1[tid];
    aL[tid] = a_; cL[tid] = b1[tid] - mu * a_;
  }
  // ---- w2 fragments (independent global loads, overlap the stats barrier)
  f16x8 w2f[9];
#pragma unroll
  for (int tap = 0; tap < 9; tap++) {
    f16x8 f;
    if (lr < 8) {
#pragma unroll
      for (int j = 0; j < 8; j++)
        f[j] = (_Float16)c2w[((lr * 32 + ic0 + j) * 3 + tap / 3) * 3 + tap % 3];
    } else {
#pragma unroll
      for (int j = 0; j < 8; j++) f[j] = (_Float16)0.f;
    }
    w2f[tap] = f;
  }
  __syncthreads();

  // ---- normalize + relu, in-place RMW on yB
  for (int i = tid * 8; i < 36992; i += 4096) {
    f16x8 raw = *(const f16x8*)(yB + i);
    int ocb = i & 31;
    f16x8 outv;
#pragma unroll
    for (int e = 0; e < 8; e++) {
      float v = (float)raw[e];
      v = fmaxf(v * aL[ocb + e] + cL[ocb + e], 0.f);
      outv[e] = (_Float16)v;
    }
    *(f16x8*)(yB + i) = outv;
  }
  __syncthreads();

  // ---- conv2: 64 row-tiles, K=288, N=8 (cols 8..15 zero)
  constexpr int OFF2[9] = {0, 32, 64, 1088, 1120, 1152, 2176, 2208, 2240};
  float s2 = 0.f, q2 = 0.f;
  for (int t = wv; t < 64; t += 8) {
    int m = t * 16 + lr;
    const unsigned short* ab = yB + ((m >> 5) * 34 + (m & 31)) * 32 + lq * 8;
    f32x4 cc = {0.f, 0.f, 0.f, 0.f};
#pragma unroll
    for (int tap = 0; tap < 9; tap++) {
      f16x8 av = *(const f16x8*)(ab + OFF2[tap]);
      cc = __builtin_amdgcn_mfma_f32_16x16x32_f16(av, w2f[tap], cc, 0, 0, 0);
    }
#pragma unroll
    for (int r = 0; r < 4; r++) {
      int mo = t * 16 + lq * 4 + r;
      float v = cc[r];
      s2 += v; q2 += v * v;
      if (lr < 8) transF[lr * 1032 + mo] = v;
    }
  }
#pragma unroll
  for (int off = 16; off < 64; off <<= 1) {
    s2 += __shfl_xor(s2, off); q2 += __shfl_xor(q2, off);
  }
  if (ln < 16) { statL[wv * 32 + ln] = s2; statL[wv * 32 + 16 + ln] = q2; }
  __syncthreads();
  if (tid < 8) {
    float s = 0.f, q = 0.f;
#pragma unroll
    for (int w = 0; w < 8; w++) { s += statL[w * 32 + tid]; q += statL[w * 32 + 16 + tid]; }
    float mu = s * (1.f / 1024.f);
    float var = q * (1.f / 1024.f) - mu * mu;
    float a_ = rsqrtf(var + 1e-5f) * g2[tid];
    aL[tid] = a_; cL[tid] = b2[tid] - mu * a_;
  }
  __syncthreads();

  // ---- sigmoid + coalesced store: wout[oc][p][pix]
  for (int idx = tid; idx < 2048; idx += 512) {
    int oc = idx >> 8, p4 = (idx & 255) << 2;
    float4 v = *(const float4*)&transF[oc * 1032 + p4];
    float a_ = aL[oc], c_ = cL[oc];
    float4 o;
    o.x = 1.f / (1.f + __expf(-(v.x * a_ + c_)));
    o.y = 1.f / (1.f + __expf(-(v.y * a_ + c_)));
    o.z = 1.f / (1.f + __expf(-(v.z * a_ + c_)));
    o.w = 1.f / (1.f + __expf(-(v.w * a_ + c_)));
    *(float4*)(wout + ((size_t)oc << 20) + ((size_t)p << 10) + p4) = o;
  }
}

// ---------------- fused attention, bf16 MFMA 16x16x32 -------------------------
__global__ __launch_bounds__(256) void attn_kernel(
    const unsigned short* __restrict__ qkv,  // bf16 bits [8192][1536]
    const float* __restrict__ wppe,          // [8][1024][1024]
    float* __restrict__ oh)                  // [8192][512] = (b,n,h,d)
{
  __shared__ __align__(16) unsigned short k_lds[64 * 72];
  __shared__ __align__(16) unsigned short v_lds[64 * 72]; // transposed [d][m ^ swz]
  __shared__ __align__(16) unsigned short p_lds[4 * 16 * 72];
  const int tid = threadIdx.x;
  const int wv = tid >> 6, ln = tid & 63;
  const int lr = ln & 15, lq = ln >> 4;
  const int b = blockIdx.y >> 3, h = blockIdx.y & 7;
  const int n0 = blockIdx.x << 6;

  const size_t qoff = (size_t)((b << 10) + n0 + (wv << 4) + lr) * 1536 + (h << 6);
  bf16x8 qf0 = *(const bf16x8*)(qkv + qoff + lq * 8);
  bf16x8 qf1 = *(const bf16x8*)(qkv + qoff + 32 + lq * 8);

  f32x4 acc[4];
#pragma unroll
  for (int dt = 0; dt < 4; dt++) acc[dt] = (f32x4){0.f, 0.f, 0.f, 0.f};
  float den[4] = {0.f, 0.f, 0.f, 0.f};
  const float* wp = wppe + ((size_t)h << 20);

  for (int m0 = 0; m0 < 1024; m0 += 64) {
    __syncthreads();
    for (int t = tid; t < 512; t += 256) {
      int m = t >> 3, dq = t & 7;
      const unsigned short* kr = qkv + (size_t)((b << 10) + m0 + m) * 1536 + 512 + (h << 6) + dq * 8;
      *(uint4*)&k_lds[m * 72 + dq * 8] = *(const uint4*)kr;
      uint4 vvv = *(const uint4*)(kr + 512);
      unsigned short tmp[8];
      *(uint4*)tmp = vvv;
#pragma unroll
      for (int i = 0; i < 8; i++) {
        int d = dq * 8 + i;
        v_lds[d * 72 + (m ^ (((d >> 3) & 7) << 3))] = tmp[i];
      }
    }
    __syncthreads();

    f32x4 s[4];
#pragma unroll
    for (int mt = 0; mt < 4; mt++) {
      const unsigned short* kb = &k_lds[(mt * 16 + lr) * 72 + lq * 8];
      f32x4 cz = (f32x4){0.f, 0.f, 0.f, 0.f};
      cz = __builtin_amdgcn_mfma_f32_16x16x32_bf16(qf0, *(const bf16x8*)kb, cz, 0, 0, 0);
      cz = __builtin_amdgcn_mfma_f32_16x16x32_bf16(qf1, *(const bf16x8*)(kb + 32), cz, 0, 0, 0);
      s[mt] = cz;
    }
#pragma unroll
    for (int mt = 0; mt < 4; mt++)
#pragma unroll
      for (int reg = 0; reg < 4; reg++) {
        int rrow = lq * 4 + reg;
        float wvl = wp[(size_t)(n0 + (wv << 4) + rrow) * 1024 + (m0 + mt * 16 + lr)];
        float pv = wvl * __expf(s[mt][reg] * 0.125f);
        den[reg] += pv;
        p_lds[((wv << 4) + rrow) * 72 + mt * 16 + lr] = f2bf(pv);
      }
    const unsigned short* pb = &p_lds[((wv << 4) + lr) * 72];
    bf16x8 pa0 = *(const bf16x8*)(pb + lq * 8);
    bf16x8 pa1 = *(const bf16x8*)(pb + 32 + lq * 8);
#pragma unroll
    for (int dt = 0; dt < 4; dt++) {
      int d = dt * 16 + lr;
      int sw = ((d >> 3) & 7) << 3;
      const unsigned short* vb = &v_lds[d * 72];
      acc[dt] = __builtin_amdgcn_mfma_f32_16x16x32_bf16(pa0, *(const bf16x8*)(vb + ((lq * 8) ^ sw)), acc[dt], 0, 0, 0);
      acc[dt] = __builtin_amdgcn_mfma_f32_16x16x32_bf16(pa1, *(const bf16x8*)(vb + ((32 + lq * 8) ^ sw)), acc[dt], 0, 0, 0);
    }
  }
#pragma unroll
  for (int off = 1; off < 16; off <<= 1)
#pragma unroll
    for (int reg = 0; reg < 4; reg++) den[reg] += __shfl_xor(den[reg], off);
#pragma unroll
  for (int dt = 0; dt < 4; dt++)
#pragma unroll
    for (int reg = 0; reg < 4; reg++) {
      size_t row = (size_t)((b << 10) + n0 + (wv << 4) + lq * 4 + reg);
      oh[row * 512 + (h << 6) + dt * 16 + lr] = acc[dt][reg] / den[reg];
    }
}

// ---------------------------------------------------------------------------
extern "C" void kernel_launch(void* const* d_in, const int* in_sizes, int n_in,
                              void* d_out, int out_size, void* d_ws, size_t ws_size,
                              hipStream_t stream) {
  (void)in_sizes; (void)n_in; (void)out_size; (void)ws_size;
  const float* x     = (const float*)d_in[0];
  const float* rpe   = (const float*)d_in[1];
  const float* wqkv  = (const float*)d_in[2];
  const float* wproj = (const float*)d_in[3];
  const float* bproj = (const float*)d_in[4];
  const float* c1w   = (const float*)d_in[5];
  // d_in[6] = c1b: cancels exactly in the following instance-norm
  const float* g1w   = (const float*)d_in[7];
  const float* g1b   = (const float*)d_in[8];
  const float* c2w   = (const float*)d_in[9];
  // d_in[10] = c2b: cancels likewise
  const float* g2w   = (const float*)d_in[11];
  const float* g2b   = (const float*)d_in[12];
  float* out = (float*)d_out;

  char* ws = (char*)d_ws;
  unsigned short* qkv_bf = (unsigned short*)ws;            // 25,165,824 B
  float* wppe = (float*)(ws + 25165824);                   // 33,554,432 B
  float* ohb  = (float*)(ws + 58720256);                   // 16,777,216 B

  // 1) qkv = x @ wqkv^T  -> bf16 (f16 MFMA)
  gemm_f16_bt<true><<<dim3(12, 64), 256, 0, stream>>>(x, wqkv, qkv_bf, nullptr, 8192, 1536, 512);

  // 2) fused conv1+IN+relu+conv2+IN+sigmoid -> w
  const int ldsC = 159232;
  hipFuncSetAttribute(reinterpret_cast<const void*>(&conv_fused),
                      hipFuncAttributeMaxDynamicSharedMemorySize, ldsC);
  conv_fused<<<1024, 512, ldsC, stream>>>(rpe, c1w, g1w, g1b, c2w, g2w, g2b, wppe);

  // 3) fused attention
  attn_kernel<<<dim3(16, 64), 256, 0, stream>>>(qkv_bf, wppe, ohb);

  // 4) out = oh @ wproj^T + bproj (f16 MFMA)
  gemm_f16_bt<false><<<dim3(4, 64), 256, 0, stream>>>(ohb, wproj, out, bproj, 8192, 512, 512);
}

// Round 5
// 222.259 us; speedup vs baseline: 3.7844x; 1.2097x over previous
//
#include <hip/hip_runtime.h>
#include <hip/hip_fp16.h>

// MPA_16698832847132 — round 4:
//  conv_fused: (a) weights staged via LDS (kills 64-line-per-load lane-divergent
//  gathers that dominated the dispatch), (b) even/odd channel split so conv1's
//  C-stores pack into conflict-free u32 stores.
// Workspace: qkv bf16 @0 (25,165,824) | w f32 @25,165,824 (33,554,432) | oh f32 @58,720,256 (16,777,216)

typedef __attribute__((ext_vector_type(8))) short bf16x8;
typedef __attribute__((ext_vector_type(8))) _Float16 f16x8;
typedef __attribute__((ext_vector_type(4))) float f32x4;

__device__ __forceinline__ unsigned short f2bf(float f) {
  unsigned u = __builtin_bit_cast(unsigned, f);
  u += 0x7FFFu + ((u >> 16) & 1u);
  return (unsigned short)(u >> 16);
}

// ---------------- C[M][N] = A[M][K] * B[N][K]^T (+bias), f16 MFMA --------------
// 128x128 tile, BK=32, 256 thr = 4 waves (2x2), per-wave 64x64 via 4x4 16x16 frags.
template<bool OUT_BF16>
__global__ __launch_bounds__(256) void gemm_f16_bt(
    const float* __restrict__ A, const float* __restrict__ B,
    void* __restrict__ Cv, const float* __restrict__ bias,
    int M, int N, int K)
{
  __shared__ __align__(16) _Float16 As[128 * 40];
  __shared__ __align__(16) _Float16 Bs[128 * 40];
  const int tid = threadIdx.x;
  const int wv = tid >> 6, ln = tid & 63, lr = ln & 15, lq = ln >> 4;
  const int wm = wv >> 1, wn = wv & 1;
  const int m0 = blockIdx.y * 128, n0 = blockIdx.x * 128;

  f32x4 acc[4][4];
#pragma unroll
  for (int i = 0; i < 4; i++)
#pragma unroll
    for (int j = 0; j < 4; j++) acc[i][j] = (f32x4){0.f, 0.f, 0.f, 0.f};

  const int sr = tid >> 1, sk = (tid & 1) * 16;
  const float* Ap = A + (size_t)(m0 + sr) * K + sk;
  const float* Bp = B + (size_t)(n0 + sr) * K + sk;

  for (int k0 = 0; k0 < K; k0 += 32) {
    float4 av0 = *(const float4*)(Ap + k0);
    float4 av1 = *(const float4*)(Ap + k0 + 4);
    float4 av2 = *(const float4*)(Ap + k0 + 8);
    float4 av3 = *(const float4*)(Ap + k0 + 12);
    float4 bv0 = *(const float4*)(Bp + k0);
    float4 bv1 = *(const float4*)(Bp + k0 + 4);
    float4 bv2 = *(const float4*)(Bp + k0 + 8);
    float4 bv3 = *(const float4*)(Bp + k0 + 12);
    __syncthreads();
    {
      f16x8 p0, p1, r0, r1;
      p0[0]=(_Float16)av0.x; p0[1]=(_Float16)av0.y; p0[2]=(_Float16)av0.z; p0[3]=(_Float16)av0.w;
      p0[4]=(_Float16)av1.x; p0[5]=(_Float16)av1.y; p0[6]=(_Float16)av1.z; p0[7]=(_Float16)av1.w;
      p1[0]=(_Float16)av2.x; p1[1]=(_Float16)av2.y; p1[2]=(_Float16)av2.z; p1[3]=(_Float16)av2.w;
      p1[4]=(_Float16)av3.x; p1[5]=(_Float16)av3.y; p1[6]=(_Float16)av3.z; p1[7]=(_Float16)av3.w;
      r0[0]=(_Float16)bv0.x; r0[1]=(_Float16)bv0.y; r0[2]=(_Float16)bv0.z; r0[3]=(_Float16)bv0.w;
      r0[4]=(_Float16)bv1.x; r0[5]=(_Float16)bv1.y; r0[6]=(_Float16)bv1.z; r0[7]=(_Float16)bv1.w;
      r1[0]=(_Float16)bv2.x; r1[1]=(_Float16)bv2.y; r1[2]=(_Float16)bv2.z; r1[3]=(_Float16)bv2.w;
      r1[4]=(_Float16)bv3.x; r1[5]=(_Float16)bv3.y; r1[6]=(_Float16)bv3.z; r1[7]=(_Float16)bv3.w;
      *(f16x8*)&As[sr * 40 + sk] = p0;
      *(f16x8*)&As[sr * 40 + sk + 8] = p1;
      *(f16x8*)&Bs[sr * 40 + sk] = r0;
      *(f16x8*)&Bs[sr * 40 + sk + 8] = r1;
    }
    __syncthreads();
    f16x8 af[4], bf[4];
#pragma unroll
    for (int mf = 0; mf < 4; mf++)
      af[mf] = *(const f16x8*)&As[(wm * 64 + mf * 16 + lr) * 40 + lq * 8];
#pragma unroll
    for (int nf = 0; nf < 4; nf++)
      bf[nf] = *(const f16x8*)&Bs[(wn * 64 + nf * 16 + lr) * 40 + lq * 8];
#pragma unroll
    for (int mf = 0; mf < 4; mf++)
#pragma unroll
      for (int nf = 0; nf < 4; nf++)
        acc[mf][nf] = __builtin_amdgcn_mfma_f32_16x16x32_f16(af[mf], bf[nf], acc[mf][nf], 0, 0, 0);
  }

#pragma unroll
  for (int mf = 0; mf < 4; mf++)
#pragma unroll
    for (int reg = 0; reg < 4; reg++) {
      const int row = m0 + wm * 64 + mf * 16 + lq * 4 + reg;
#pragma unroll
      for (int nf = 0; nf < 4; nf++) {
        const int col = n0 + wn * 64 + nf * 16 + lr;
        float v = acc[mf][nf][reg];
        if (bias) v += bias[col];
        if (OUT_BF16) ((unsigned short*)Cv)[(size_t)row * N + col] = f2bf(v);
        else          ((float*)Cv)[(size_t)row * N + col] = v;
      }
    }
}

// ---------------- fused conv1+IN+relu+conv2+IN+sigmoid, f16 MFMA ---------------
// One image per block (grid 1024), 512 threads = 8 waves (2/SIMD).
// LDS: inA half[1296][32] @0 (82,944) | yB half[1156][32] @82,944 (73,984)
//      statL f32[512] @156,928 | aL/cL f32[32+32] @158,976 -> total 159,232
// Overlays: wH1(18,432 B)+wH2(4,608 B) on yB (consumed into regs before conv1);
//           transF f32[8][1032] on inA (phase 2).
// Channel split: col-tile0 -> even channels (oc=2*lr), col-tile1 -> odd (2*lr+1),
// so each lane's C-pair packs into one u32 store at yB[mo*32+2*lr] (conflict-free).
__global__ __launch_bounds__(512, 1) void conv_fused(
    const float* __restrict__ rpe,
    const float* __restrict__ c1w, const float* __restrict__ g1, const float* __restrict__ b1,
    const float* __restrict__ c2w, const float* __restrict__ g2, const float* __restrict__ b2,
    float* __restrict__ wout)
{
  extern __shared__ __align__(16) char smem[];
  unsigned short* inA = (unsigned short*)smem;
  unsigned short* yB  = (unsigned short*)(smem + 82944);
  unsigned short* wH1 = yB;          // overlay: 9216 halves [tap][oc][ic]
  unsigned short* wH2 = yB + 9216;   // overlay: 2304 halves [tap][oc][ic]
  float* statL = (float*)(smem + 156928);   // 512 f32
  float* aL    = (float*)(smem + 158976);   // 32
  float* cL    = aL + 32;                   // 32
  float* transF = (float*)smem;             // phase-2 overlay [8][1032]

  const int tid = threadIdx.x;
  const int wv = tid >> 6, ln = tid & 63;
  const int lr = ln & 15, lq = ln >> 4;
  const int p = blockIdx.x;

  // ---- stage input: rpe crop row -> LDS f16, channel-inner [1296][32]
  const float* src = rpe + (size_t)(((p >> 5) + 2) * 36 + (p & 31) + 2) * 41472;
  for (int t = tid; t < 10368; t += 512) {
    int pix = t >> 3, dq = (t & 7) << 2;
    float4 v = *(const float4*)(src + pix * 32 + dq);
    __half2 h0 = __floats2half2_rn(v.x, v.y);
    __half2 h1 = __floats2half2_rn(v.z, v.w);
    uint2 u; u.x = __builtin_bit_cast(unsigned, h0); u.y = __builtin_bit_cast(unsigned, h1);
    *(uint2*)(inA + pix * 32 + dq) = u;
  }
  // ---- stage weights coalesced: c1w[9216], c2w[2304] f32 -> LDS f16 [tap][oc][ic]
  for (int t = tid; t < 9216; t += 512) {
    int oc = t / 288, rem = t - oc * 288;
    int ic = rem / 9, tap = rem - ic * 9;
    wH1[(tap * 32 + oc) * 32 + ic] = __half_as_ushort(__float2half(c1w[t]));
  }
  for (int t = tid; t < 2304; t += 512) {
    int oc = t / 288, rem = t - oc * 288;
    int ic = rem / 9, tap = rem - ic * 9;
    wH2[(tap * 8 + oc) * 32 + ic] = __half_as_ushort(__float2half(c2w[t]));
  }
  __syncthreads();

  // ---- weight fragments from LDS (ct=0: oc=2*lr even; ct=1: oc=2*lr+1 odd)
  f16x8 w1f[2][9];
  const int ic0 = lq * 8;
#pragma unroll
  for (int ct = 0; ct < 2; ct++) {
    int oc = 2 * lr + ct;
#pragma unroll
    for (int tap = 0; tap < 9; tap++)
      w1f[ct][tap] = *(const f16x8*)&wH1[(tap * 32 + oc) * 32 + ic0];
  }
  f16x8 w2f[9];
#pragma unroll
  for (int tap = 0; tap < 9; tap++) {
    if (lr < 8) w2f[tap] = *(const f16x8*)&wH2[(tap * 8 + lr) * 32 + ic0];
    else {
      f16x8 z;
#pragma unroll
      for (int j = 0; j < 8; j++) z[j] = (_Float16)0.f;
      w2f[tap] = z;
    }
  }
  __syncthreads();  // all wH reads done before conv1 overwrites yB

  // ---- conv1: 73 row-tiles of 16 out-pixels, K=288 (9 taps x 32ic), N=32
  constexpr int OFF1[9] = {0, 32, 64, 1152, 1184, 1216, 2304, 2336, 2368};
  float s0 = 0.f, q0 = 0.f, s1 = 0.f, q1 = 0.f;
  for (int t = wv; t < 73; t += 8) {
    int m = t * 16 + lr;
    int ms = m < 1155 ? m : 1155;
    const unsigned short* ab = inA + ((ms / 34) * 36 + (ms % 34)) * 32 + lq * 8;
    f32x4 c0 = {0.f, 0.f, 0.f, 0.f}, c1v = {0.f, 0.f, 0.f, 0.f};
#pragma unroll
    for (int tap = 0; tap < 9; tap++) {
      f16x8 av = *(const f16x8*)(ab + OFF1[tap]);
      c0  = __builtin_amdgcn_mfma_f32_16x16x32_f16(av, w1f[0][tap], c0, 0, 0, 0);
      c1v = __builtin_amdgcn_mfma_f32_16x16x32_f16(av, w1f[1][tap], c1v, 0, 0, 0);
    }
#pragma unroll
    for (int r = 0; r < 4; r++) {
      int mo = t * 16 + lq * 4 + r;
      if (mo < 1156) {
        float v0 = c0[r], v1 = c1v[r];   // channels 2*lr, 2*lr+1
        unsigned u = (unsigned)__half_as_ushort(__float2half(v0))
                   | ((unsigned)__half_as_ushort(__float2half(v1)) << 16);
        *(unsigned*)&yB[mo * 32 + lr * 2] = u;
        s0 += v0; q0 += v0 * v0; s1 += v1; q1 += v1 * v1;
      }
    }
  }
  // stats reduce: lanes sharing lr (xor 16, 32). s0/q0 -> ch 2*lr, s1/q1 -> ch 2*lr+1
#pragma unroll
  for (int off = 16; off < 64; off <<= 1) {
    s0 += __shfl_xor(s0, off); q0 += __shfl_xor(q0, off);
    s1 += __shfl_xor(s1, off); q1 += __shfl_xor(q1, off);
  }
  if (ln < 16) {
    float* st = statL + wv * 64;
    st[ln] = s0; st[16 + ln] = q0; st[32 + ln] = s1; st[48 + ln] = q1;
  }
  __syncthreads();
  if (tid < 32) {
    int cti = tid >> 4, lri = tid & 15;   // cti=0: even set (ch=2*lri), 1: odd (2*lri+1)
    float s = 0.f, q = 0.f;
#pragma unroll
    for (int w = 0; w < 8; w++) {
      s += statL[w * 64 + cti * 32 + lri];
      q += statL[w * 64 + cti * 32 + 16 + lri];
    }
    int ch = 2 * lri + cti;
    float mu = s * (1.f / 1156.f);
    float var = q * (1.f / 1156.f) - mu * mu;
    float a_ = rsqrtf(var + 1e-5f) * g1[ch];
    aL[ch] = a_; cL[ch] = b1[ch] - mu * a_;
  }
  __syncthreads();

  // ---- normalize + relu, in-place RMW on yB (natural channel order)
  for (int i = tid * 8; i < 36992; i += 4096) {
    f16x8 raw = *(const f16x8*)(yB + i);
    int ocb = i & 31;
    f16x8 outv;
#pragma unroll
    for (int e = 0; e < 8; e++) {
      float v = (float)raw[e];
      v = fmaxf(v * aL[ocb + e] + cL[ocb + e], 0.f);
      outv[e] = (_Float16)v;
    }
    *(f16x8*)(yB + i) = outv;
  }
  __syncthreads();

  // ---- conv2: 64 row-tiles, K=288, N=8 (cols 8..15 zero)
  constexpr int OFF2[9] = {0, 32, 64, 1088, 1120, 1152, 2176, 2208, 2240};
  float s2 = 0.f, q2 = 0.f;
  for (int t = wv; t < 64; t += 8) {
    int m = t * 16 + lr;
    const unsigned short* ab = yB + ((m >> 5) * 34 + (m & 31)) * 32 + lq * 8;
    f32x4 cc = {0.f, 0.f, 0.f, 0.f};
#pragma unroll
    for (int tap = 0; tap < 9; tap++) {
      f16x8 av = *(const f16x8*)(ab + OFF2[tap]);
      cc = __builtin_amdgcn_mfma_f32_16x16x32_f16(av, w2f[tap], cc, 0, 0, 0);
    }
#pragma unroll
    for (int r = 0; r < 4; r++) {
      int mo = t * 16 + lq * 4 + r;
      float v = cc[r];
      s2 += v; q2 += v * v;
      if (lr < 8) transF[lr * 1032 + mo] = v;
    }
  }
#pragma unroll
  for (int off = 16; off < 64; off <<= 1) {
    s2 += __shfl_xor(s2, off); q2 += __shfl_xor(q2, off);
  }
  if (ln < 16) { statL[wv * 32 + ln] = s2; statL[wv * 32 + 16 + ln] = q2; }
  __syncthreads();
  if (tid < 8) {
    float s = 0.f, q = 0.f;
#pragma unroll
    for (int w = 0; w < 8; w++) { s += statL[w * 32 + tid]; q += statL[w * 32 + 16 + tid]; }
    float mu = s * (1.f / 1024.f);
    float var = q * (1.f / 1024.f) - mu * mu;
    float a_ = rsqrtf(var + 1e-5f) * g2[tid];
    aL[tid] = a_; cL[tid] = b2[tid] - mu * a_;
  }
  __syncthreads();

  // ---- sigmoid + coalesced store: wout[oc][p][pix]
  for (int idx = tid; idx < 2048; idx += 512) {
    int oc = idx >> 8, p4 = (idx & 255) << 2;
    float4 v = *(const float4*)&transF[oc * 1032 + p4];
    float a_ = aL[oc], c_ = cL[oc];
    float4 o;
    o.x = 1.f / (1.f + __expf(-(v.x * a_ + c_)));
    o.y = 1.f / (1.f + __expf(-(v.y * a_ + c_)));
    o.z = 1.f / (1.f + __expf(-(v.z * a_ + c_)));
    o.w = 1.f / (1.f + __expf(-(v.w * a_ + c_)));
    *(float4*)(wout + ((size_t)oc << 20) + ((size_t)p << 10) + p4) = o;
  }
}

// ---------------- fused attention, bf16 MFMA 16x16x32 -------------------------
__global__ __launch_bounds__(256) void attn_kernel(
    const unsigned short* __restrict__ qkv,  // bf16 bits [8192][1536]
    const float* __restrict__ wppe,          // [8][1024][1024]
    float* __restrict__ oh)                  // [8192][512] = (b,n,h,d)
{
  __shared__ __align__(16) unsigned short k_lds[64 * 72];
  __shared__ __align__(16) unsigned short v_lds[64 * 72]; // transposed [d][m ^ swz]
  __shared__ __align__(16) unsigned short p_lds[4 * 16 * 72];
  const int tid = threadIdx.x;
  const int wv = tid >> 6, ln = tid & 63;
  const int lr = ln & 15, lq = ln >> 4;
  const int b = blockIdx.y >> 3, h = blockIdx.y & 7;
  const int n0 = blockIdx.x << 6;

  const size_t qoff = (size_t)((b << 10) + n0 + (wv << 4) + lr) * 1536 + (h << 6);
  bf16x8 qf0 = *(const bf16x8*)(qkv + qoff + lq * 8);
  bf16x8 qf1 = *(const bf16x8*)(qkv + qoff + 32 + lq * 8);

  f32x4 acc[4];
#pragma unroll
  for (int dt = 0; dt < 4; dt++) acc[dt] = (f32x4){0.f, 0.f, 0.f, 0.f};
  float den[4] = {0.f, 0.f, 0.f, 0.f};
  const float* wp = wppe + ((size_t)h << 20);

  for (int m0 = 0; m0 < 1024; m0 += 64) {
    __syncthreads();
    for (int t = tid; t < 512; t += 256) {
      int m = t >> 3, dq = t & 7;
      const unsigned short* kr = qkv + (size_t)((b << 10) + m0 + m) * 1536 + 512 + (h << 6) + dq * 8;
      *(uint4*)&k_lds[m * 72 + dq * 8] = *(const uint4*)kr;
      uint4 vvv = *(const uint4*)(kr + 512);
      unsigned short tmp[8];
      *(uint4*)tmp = vvv;
#pragma unroll
      for (int i = 0; i < 8; i++) {
        int d = dq * 8 + i;
        v_lds[d * 72 + (m ^ (((d >> 3) & 7) << 3))] = tmp[i];
      }
    }
    __syncthreads();

    f32x4 s[4];
#pragma unroll
    for (int mt = 0; mt < 4; mt++) {
      const unsigned short* kb = &k_lds[(mt * 16 + lr) * 72 + lq * 8];
      f32x4 cz = (f32x4){0.f, 0.f, 0.f, 0.f};
      cz = __builtin_amdgcn_mfma_f32_16x16x32_bf16(qf0, *(const bf16x8*)kb, cz, 0, 0, 0);
      cz = __builtin_amdgcn_mfma_f32_16x16x32_bf16(qf1, *(const bf16x8*)(kb + 32), cz, 0, 0, 0);
      s[mt] = cz;
    }
#pragma unroll
    for (int mt = 0; mt < 4; mt++)
#pragma unroll
      for (int reg = 0; reg < 4; reg++) {
        int rrow = lq * 4 + reg;
        float wvl = wp[(size_t)(n0 + (wv << 4) + rrow) * 1024 + (m0 + mt * 16 + lr)];
        float pv = wvl * __expf(s[mt][reg] * 0.125f);
        den[reg] += pv;
        p_lds[((wv << 4) + rrow) * 72 + mt * 16 + lr] = f2bf(pv);
      }
    const unsigned short* pb = &p_lds[((wv << 4) + lr) * 72];
    bf16x8 pa0 = *(const bf16x8*)(pb + lq * 8);
    bf16x8 pa1 = *(const bf16x8*)(pb + 32 + lq * 8);
#pragma unroll
    for (int dt = 0; dt < 4; dt++) {
      int d = dt * 16 + lr;
      int sw = ((d >> 3) & 7) << 3;
      const unsigned short* vb = &v_lds[d * 72];
      acc[dt] = __builtin_amdgcn_mfma_f32_16x16x32_bf16(pa0, *(const bf16x8*)(vb + ((lq * 8) ^ sw)), acc[dt], 0, 0, 0);
      acc[dt] = __builtin_amdgcn_mfma_f32_16x16x32_bf16(pa1, *(const bf16x8*)(vb + ((32 + lq * 8) ^ sw)), acc[dt], 0, 0, 0);
    }
  }
#pragma unroll
  for (int off = 1; off < 16; off <<= 1)
#pragma unroll
    for (int reg = 0; reg < 4; reg++) den[reg] += __shfl_xor(den[reg], off);
#pragma unroll
  for (int dt = 0; dt < 4; dt++)
#pragma unroll
    for (int reg = 0; reg < 4; reg++) {
      size_t row = (size_t)((b << 10) + n0 + (wv << 4) + lq * 4 + reg);
      oh[row * 512 + (h << 6) + dt * 16 + lr] = acc[dt][reg] / den[reg];
    }
}

// ---------------------------------------------------------------------------
extern "C" void kernel_launch(void* const* d_in, const int* in_sizes, int n_in,
                              void* d_out, int out_size, void* d_ws, size_t ws_size,
                              hipStream_t stream) {
  (void)in_sizes; (void)n_in; (void)out_size; (void)ws_size;
  const float* x     = (const float*)d_in[0];
  const float* rpe   = (const float*)d_in[1];
  const float* wqkv  = (const float*)d_in[2];
  const float* wproj = (const float*)d_in[3];
  const float* bproj = (const float*)d_in[4];
  const float* c1w   = (const float*)d_in[5];
  // d_in[6] = c1b: cancels exactly in the following instance-norm
  const float* g1w   = (const float*)d_in[7];
  const float* g1b   = (const float*)d_in[8];
  const float* c2w   = (const float*)d_in[9];
  // d_in[10] = c2b: cancels likewise
  const float* g2w   = (const float*)d_in[11];
  const float* g2b   = (const float*)d_in[12];
  float* out = (float*)d_out;

  char* ws = (char*)d_ws;
  unsigned short* qkv_bf = (unsigned short*)ws;            // 25,165,824 B
  float* wppe = (float*)(ws + 25165824);                   // 33,554,432 B
  float* ohb  = (float*)(ws + 58720256);                   // 16,777,216 B

  // 1) qkv = x @ wqkv^T  -> bf16 (f16 MFMA)
  gemm_f16_bt<true><<<dim3(12, 64), 256, 0, stream>>>(x, wqkv, qkv_bf, nullptr, 8192, 1536, 512);

  // 2) fused conv1+IN+relu+conv2+IN+sigmoid -> w
  const int ldsC = 159232;
  hipFuncSetAttribute(reinterpret_cast<const void*>(&conv_fused),
                      hipFuncAttributeMaxDynamicSharedMemorySize, ldsC);
  conv_fused<<<1024, 512, ldsC, stream>>>(rpe, c1w, g1w, g1b, c2w, g2w, g2b, wppe);

  // 3) fused attention
  attn_kernel<<<dim3(16, 64), 256, 0, stream>>>(qkv_bf, wppe, ohb);

  // 4) out = oh @ wproj^T + bproj (f16 MFMA)
  gemm_f16_bt<false><<<dim3(4, 64), 256, 0, stream>>>(ohb, wproj, out, bproj, 8192, 512, 512);
}

// Round 6
// 217.765 us; speedup vs baseline: 3.8625x; 1.0206x over previous
//
#include <hip/hip_runtime.h>
#include <hip/hip_fp16.h>

// MPA_16698832847132 — round 5:
//  conv_fused: channel-major LDS (kills 8-way A-read bank conflicts, constant tap
//  offsets), 1024 threads (16 waves, 4/SIMD), cross-wave stats via LDS atomicAdd.
// Workspace: qkv bf16 @0 (25,165,824) | w f32 @25,165,824 (33,554,432) | oh f32 @58,720,256 (16,777,216)

typedef __attribute__((ext_vector_type(8))) short bf16x8;
typedef __attribute__((ext_vector_type(8))) _Float16 f16x8;
typedef __attribute__((ext_vector_type(4))) float f32x4;

__device__ __forceinline__ unsigned short f2bf(float f) {
  unsigned u = __builtin_bit_cast(unsigned, f);
  u += 0x7FFFu + ((u >> 16) & 1u);
  return (unsigned short)(u >> 16);
}

// ---------------- C[M][N] = A[M][K] * B[N][K]^T (+bias), f16 MFMA --------------
// 128x128 tile, BK=32, 256 thr = 4 waves (2x2), per-wave 64x64 via 4x4 16x16 frags.
template<bool OUT_BF16>
__global__ __launch_bounds__(256) void gemm_f16_bt(
    const float* __restrict__ A, const float* __restrict__ B,
    void* __restrict__ Cv, const float* __restrict__ bias,
    int M, int N, int K)
{
  __shared__ __align__(16) _Float16 As[128 * 40];
  __shared__ __align__(16) _Float16 Bs[128 * 40];
  const int tid = threadIdx.x;
  const int wv = tid >> 6, ln = tid & 63, lr = ln & 15, lq = ln >> 4;
  const int wm = wv >> 1, wn = wv & 1;
  const int m0 = blockIdx.y * 128, n0 = blockIdx.x * 128;

  f32x4 acc[4][4];
#pragma unroll
  for (int i = 0; i < 4; i++)
#pragma unroll
    for (int j = 0; j < 4; j++) acc[i][j] = (f32x4){0.f, 0.f, 0.f, 0.f};

  const int sr = tid >> 1, sk = (tid & 1) * 16;
  const float* Ap = A + (size_t)(m0 + sr) * K + sk;
  const float* Bp = B + (size_t)(n0 + sr) * K + sk;

  for (int k0 = 0; k0 < K; k0 += 32) {
    float4 av0 = *(const float4*)(Ap + k0);
    float4 av1 = *(const float4*)(Ap + k0 + 4);
    float4 av2 = *(const float4*)(Ap + k0 + 8);
    float4 av3 = *(const float4*)(Ap + k0 + 12);
    float4 bv0 = *(const float4*)(Bp + k0);
    float4 bv1 = *(const float4*)(Bp + k0 + 4);
    float4 bv2 = *(const float4*)(Bp + k0 + 8);
    float4 bv3 = *(const float4*)(Bp + k0 + 12);
    __syncthreads();
    {
      f16x8 p0, p1, r0, r1;
      p0[0]=(_Float16)av0.x; p0[1]=(_Float16)av0.y; p0[2]=(_Float16)av0.z; p0[3]=(_Float16)av0.w;
      p0[4]=(_Float16)av1.x; p0[5]=(_Float16)av1.y; p0[6]=(_Float16)av1.z; p0[7]=(_Float16)av1.w;
      p1[0]=(_Float16)av2.x; p1[1]=(_Float16)av2.y; p1[2]=(_Float16)av2.z; p1[3]=(_Float16)av2.w;
      p1[4]=(_Float16)av3.x; p1[5]=(_Float16)av3.y; p1[6]=(_Float16)av3.z; p1[7]=(_Float16)av3.w;
      r0[0]=(_Float16)bv0.x; r0[1]=(_Float16)bv0.y; r0[2]=(_Float16)bv0.z; r0[3]=(_Float16)bv0.w;
      r0[4]=(_Float16)bv1.x; r0[5]=(_Float16)bv1.y; r0[6]=(_Float16)bv1.z; r0[7]=(_Float16)bv1.w;
      r1[0]=(_Float16)bv2.x; r1[1]=(_Float16)bv2.y; r1[2]=(_Float16)bv2.z; r1[3]=(_Float16)bv2.w;
      r1[4]=(_Float16)bv3.x; r1[5]=(_Float16)bv3.y; r1[6]=(_Float16)bv3.z; r1[7]=(_Float16)bv3.w;
      *(f16x8*)&As[sr * 40 + sk] = p0;
      *(f16x8*)&As[sr * 40 + sk + 8] = p1;
      *(f16x8*)&Bs[sr * 40 + sk] = r0;
      *(f16x8*)&Bs[sr * 40 + sk + 8] = r1;
    }
    __syncthreads();
    f16x8 af[4], bf[4];
#pragma unroll
    for (int mf = 0; mf < 4; mf++)
      af[mf] = *(const f16x8*)&As[(wm * 64 + mf * 16 + lr) * 40 + lq * 8];
#pragma unroll
    for (int nf = 0; nf < 4; nf++)
      bf[nf] = *(const f16x8*)&Bs[(wn * 64 + nf * 16 + lr) * 40 + lq * 8];
#pragma unroll
    for (int mf = 0; mf < 4; mf++)
#pragma unroll
      for (int nf = 0; nf < 4; nf++)
        acc[mf][nf] = __builtin_amdgcn_mfma_f32_16x16x32_f16(af[mf], bf[nf], acc[mf][nf], 0, 0, 0);
  }

#pragma unroll
  for (int mf = 0; mf < 4; mf++)
#pragma unroll
    for (int reg = 0; reg < 4; reg++) {
      const int row = m0 + wm * 64 + mf * 16 + lq * 4 + reg;
#pragma unroll
      for (int nf = 0; nf < 4; nf++) {
        const int col = n0 + wn * 64 + nf * 16 + lr;
        float v = acc[mf][nf][reg];
        if (bias) v += bias[col];
        if (OUT_BF16) ((unsigned short*)Cv)[(size_t)row * N + col] = f2bf(v);
        else          ((float*)Cv)[(size_t)row * N + col] = v;
      }
    }
}

// ---------------- fused conv1+IN+relu+conv2+IN+sigmoid, f16 MFMA ---------------
// One image per block (grid 1024), 1024 threads = 16 waves (4/SIMD).
// Channel-major LDS: inA[g][1296][8] @0 (82,944) | yB[g][1156][8] @82,944 (73,984)
//   wH2 half[2304] @156,928 (4,608, persistent) | statA f32[64] @161,536
//   aL/cL f32[32+32] @161,792 -> total 162,048
// Overlays: wH1 (18,432 B) on yB (consumed to regs pre-conv1); transF f32[8][1032] on inA.
__global__ __launch_bounds__(1024, 1) void conv_fused(
    const float* __restrict__ rpe,
    const float* __restrict__ c1w, const float* __restrict__ g1, const float* __restrict__ b1,
    const float* __restrict__ c2w, const float* __restrict__ g2, const float* __restrict__ b2,
    float* __restrict__ wout)
{
  extern __shared__ __align__(16) char smem[];
  unsigned short* inA = (unsigned short*)smem;              // 4 x 10368 halves
  unsigned short* yB  = (unsigned short*)(smem + 82944);    // 4 x 9248 halves
  unsigned short* wH1 = yB;                                 // overlay: 9216 halves
  unsigned short* wH2 = (unsigned short*)(smem + 156928);   // 2304 halves (persistent)
  float* statA = (float*)(smem + 161536);                   // 64
  float* aL    = (float*)(smem + 161792);                   // 32
  float* cL    = aL + 32;                                   // 32
  float* transF = (float*)smem;                             // phase-2 overlay [8][1032]

  const int tid = threadIdx.x;
  const int wv = tid >> 6, ln = tid & 63;
  const int lr = ln & 15, lq = ln >> 4;
  const int p = blockIdx.x;

  if (tid < 64) statA[tid] = 0.f;

  // ---- stage input: rpe crop -> LDS f16 channel-major [g][pix][8]
  const float* src = rpe + (size_t)(((p >> 5) + 2) * 36 + (p & 31) + 2) * 41472;
  for (int t = tid; t < 10368; t += 1024) {
    int pix = t >> 3, dq = (t & 7) << 2;
    float4 v = *(const float4*)(src + pix * 32 + dq);
    __half2 h0 = __floats2half2_rn(v.x, v.y);
    __half2 h1 = __floats2half2_rn(v.z, v.w);
    uint2 u; u.x = __builtin_bit_cast(unsigned, h0); u.y = __builtin_bit_cast(unsigned, h1);
    *(uint2*)&inA[(dq >> 3) * 10368 + pix * 8 + (dq & 7)] = u;
  }
  // ---- stage weights coalesced -> LDS f16 [tap][oc][ic]
  for (int t = tid; t < 9216; t += 1024) {
    int oc = t / 288, rem = t - oc * 288;
    int ic = rem / 9, tap = rem - ic * 9;
    wH1[(tap * 32 + oc) * 32 + ic] = __half_as_ushort(__float2half(c1w[t]));
  }
  for (int t = tid; t < 2304; t += 1024) {
    int oc = t / 288, rem = t - oc * 288;
    int ic = rem / 9, tap = rem - ic * 9;
    wH2[(tap * 8 + oc) * 32 + ic] = __half_as_ushort(__float2half(c2w[t]));
  }
  __syncthreads();

  // ---- w1 fragments (ct=0: oc=2*lr; ct=1: oc=2*lr+1)
  f16x8 w1f[2][9];
  const int ic0 = lq * 8;
#pragma unroll
  for (int ct = 0; ct < 2; ct++) {
    int oc = 2 * lr + ct;
#pragma unroll
    for (int tap = 0; tap < 9; tap++)
      w1f[ct][tap] = *(const f16x8*)&wH1[(tap * 32 + oc) * 32 + ic0];
  }
  __syncthreads();  // wH1 reads done before conv1 overwrites yB

  // ---- conv1: 73 row-tiles of 16 out-pixels, K=288, N=32
  constexpr int OFF1[9] = {0, 8, 16, 288, 296, 304, 576, 584, 592};
  float s0 = 0.f, q0 = 0.f, s1 = 0.f, q1 = 0.f;
  const unsigned short* inAg = inA + lq * 10368;
  for (int t = wv; t < 73; t += 16) {
    int m = t * 16 + lr;
    int ms = m < 1155 ? m : 1155;
    const unsigned short* ab = inAg + ((ms / 34) * 36 + (ms % 34)) * 8;
    f32x4 c0 = {0.f, 0.f, 0.f, 0.f}, c1v = {0.f, 0.f, 0.f, 0.f};
#pragma unroll
    for (int tap = 0; tap < 9; tap++) {
      f16x8 av = *(const f16x8*)(ab + OFF1[tap]);
      c0  = __builtin_amdgcn_mfma_f32_16x16x32_f16(av, w1f[0][tap], c0, 0, 0, 0);
      c1v = __builtin_amdgcn_mfma_f32_16x16x32_f16(av, w1f[1][tap], c1v, 0, 0, 0);
    }
#pragma unroll
    for (int r = 0; r < 4; r++) {
      int mo = t * 16 + lq * 4 + r;
      if (mo < 1156) {
        float v0 = c0[r], v1 = c1v[r];   // logical channels 2*lr, 2*lr+1
        unsigned u = (unsigned)__half_as_ushort(__float2half(v0))
                   | ((unsigned)__half_as_ushort(__float2half(v1)) << 16);
        *(unsigned*)&yB[(lr >> 2) * 9248 + mo * 8 + ((lr * 2) & 7)] = u;
        s0 += v0; q0 += v0 * v0; s1 += v1; q1 += v1 * v1;
      }
    }
  }
#pragma unroll
  for (int off = 16; off < 64; off <<= 1) {
    s0 += __shfl_xor(s0, off); q0 += __shfl_xor(q0, off);
    s1 += __shfl_xor(s1, off); q1 += __shfl_xor(q1, off);
  }
  if (ln < 16) {
    atomicAdd(&statA[ln], s0);      atomicAdd(&statA[16 + ln], q0);
    atomicAdd(&statA[32 + ln], s1); atomicAdd(&statA[48 + ln], q1);
  }
  __syncthreads();
  if (tid < 32) {
    int cti = tid >> 4, lri = tid & 15;   // cti=0: ch=2*lri (s0/q0), cti=1: ch=2*lri+1
    float s = statA[cti * 32 + lri];
    float q = statA[cti * 32 + 16 + lri];
    int ch = 2 * lri + cti;
    float mu = s * (1.f / 1156.f);
    float var = q * (1.f / 1156.f) - mu * mu;
    float a_ = rsqrtf(var + 1e-5f) * g1[ch];
    aL[ch] = a_; cL[ch] = b1[ch] - mu * a_;
  }
  if (tid < 16) statA[tid] = 0.f;  // conv2 stat slots (safe: statA[0..15] only read by tid<16 above, in program order)
  __syncthreads();

  // ---- normalize + relu, in-place RMW on yB (channel-major: group g = logical ch g*8..)
  {
    int g = tid >> 8, ocb = g * 8;
    unsigned short* yg = yB + g * 9248;
    for (int pix = (tid & 255); pix < 1156; pix += 256) {
      f16x8 raw = *(const f16x8*)&yg[pix * 8];
      f16x8 outv;
#pragma unroll
      for (int e = 0; e < 8; e++) {
        float v = (float)raw[e];
        v = fmaxf(v * aL[ocb + e] + cL[ocb + e], 0.f);
        outv[e] = (_Float16)v;
      }
      *(f16x8*)&yg[pix * 8] = outv;
    }
  }
  __syncthreads();

  // ---- conv2: 64 row-tiles, K=288, N=8 (lanes lr>=8 compute duplicates, never stored)
  constexpr int OFF2[9] = {0, 8, 16, 272, 280, 288, 544, 552, 560};
  const unsigned short* yBg = yB + lq * 9248;
  float s2 = 0.f, q2 = 0.f;
  for (int t = wv; t < 64; t += 16) {
    int m = t * 16 + lr;
    const unsigned short* ab = yBg + ((m >> 5) * 34 + (m & 31)) * 8;
    f32x4 cc = {0.f, 0.f, 0.f, 0.f};
#pragma unroll
    for (int tap = 0; tap < 9; tap++) {
      f16x8 av = *(const f16x8*)(ab + OFF2[tap]);
      f16x8 wf = *(const f16x8*)&wH2[(tap * 8 + (lr & 7)) * 32 + ic0];
      cc = __builtin_amdgcn_mfma_f32_16x16x32_f16(av, wf, cc, 0, 0, 0);
    }
#pragma unroll
    for (int r = 0; r < 4; r++) {
      int mo = t * 16 + lq * 4 + r;
      float v = cc[r];
      if (lr < 8) {
        s2 += v; q2 += v * v;
        transF[lr * 1032 + mo] = v;
      }
    }
  }
#pragma unroll
  for (int off = 16; off < 64; off <<= 1) {
    s2 += __shfl_xor(s2, off); q2 += __shfl_xor(q2, off);
  }
  if (ln < 8) { atomicAdd(&statA[ln], s2); atomicAdd(&statA[8 + ln], q2); }
  __syncthreads();
  if (tid < 8) {
    float s = statA[tid], q = statA[8 + tid];
    float mu = s * (1.f / 1024.f);
    float var = q * (1.f / 1024.f) - mu * mu;
    float a_ = rsqrtf(var + 1e-5f) * g2[tid];
    aL[tid] = a_; cL[tid] = b2[tid] - mu * a_;
  }
  __syncthreads();

  // ---- sigmoid + coalesced store: wout[oc][p][pix]
  for (int idx = tid; idx < 2048; idx += 1024) {
    int oc = idx >> 8, p4 = (idx & 255) << 2;
    float4 v = *(const float4*)&transF[oc * 1032 + p4];
    float a_ = aL[oc], c_ = cL[oc];
    float4 o;
    o.x = 1.f / (1.f + __expf(-(v.x * a_ + c_)));
    o.y = 1.f / (1.f + __expf(-(v.y * a_ + c_)));
    o.z = 1.f / (1.f + __expf(-(v.z * a_ + c_)));
    o.w = 1.f / (1.f + __expf(-(v.w * a_ + c_)));
    *(float4*)(wout + ((size_t)oc << 20) + ((size_t)p << 10) + p4) = o;
  }
}

// ---------------- fused attention, bf16 MFMA 16x16x32 -------------------------
__global__ __launch_bounds__(256) void attn_kernel(
    const unsigned short* __restrict__ qkv,  // bf16 bits [8192][1536]
    const float* __restrict__ wppe,          // [8][1024][1024]
    float* __restrict__ oh)                  // [8192][512] = (b,n,h,d)
{
  __shared__ __align__(16) unsigned short k_lds[64 * 72];
  __shared__ __align__(16) unsigned short v_lds[64 * 72]; // transposed [d][m ^ swz]
  __shared__ __align__(16) unsigned short p_lds[4 * 16 * 72];
  const int tid = threadIdx.x;
  const int wv = tid >> 6, ln = tid & 63;
  const int lr = ln & 15, lq = ln >> 4;
  const int b = blockIdx.y >> 3, h = blockIdx.y & 7;
  const int n0 = blockIdx.x << 6;

  const size_t qoff = (size_t)((b << 10) + n0 + (wv << 4) + lr) * 1536 + (h << 6);
  bf16x8 qf0 = *(const bf16x8*)(qkv + qoff + lq * 8);
  bf16x8 qf1 = *(const bf16x8*)(qkv + qoff + 32 + lq * 8);

  f32x4 acc[4];
#pragma unroll
  for (int dt = 0; dt < 4; dt++) acc[dt] = (f32x4){0.f, 0.f, 0.f, 0.f};
  float den[4] = {0.f, 0.f, 0.f, 0.f};
  const float* wp = wppe + ((size_t)h << 20);

  for (int m0 = 0; m0 < 1024; m0 += 64) {
    __syncthreads();
    for (int t = tid; t < 512; t += 256) {
      int m = t >> 3, dq = t & 7;
      const unsigned short* kr = qkv + (size_t)((b << 10) + m0 + m) * 1536 + 512 + (h << 6) + dq * 8;
      *(uint4*)&k_lds[m * 72 + dq * 8] = *(const uint4*)kr;
      uint4 vvv = *(const uint4*)(kr + 512);
      unsigned short tmp[8];
      *(uint4*)tmp = vvv;
#pragma unroll
      for (int i = 0; i < 8; i++) {
        int d = dq * 8 + i;
        v_lds[d * 72 + (m ^ (((d >> 3) & 7) << 3))] = tmp[i];
      }
    }
    __syncthreads();

    f32x4 s[4];
#pragma unroll
    for (int mt = 0; mt < 4; mt++) {
      const unsigned short* kb = &k_lds[(mt * 16 + lr) * 72 + lq * 8];
      f32x4 cz = (f32x4){0.f, 0.f, 0.f, 0.f};
      cz = __builtin_amdgcn_mfma_f32_16x16x32_bf16(qf0, *(const bf16x8*)kb, cz, 0, 0, 0);
      cz = __builtin_amdgcn_mfma_f32_16x16x32_bf16(qf1, *(const bf16x8*)(kb + 32), cz, 0, 0, 0);
      s[mt] = cz;
    }
#pragma unroll
    for (int mt = 0; mt < 4; mt++)
#pragma unroll
      for (int reg = 0; reg < 4; reg++) {
        int rrow = lq * 4 + reg;
        float wvl = wp[(size_t)(n0 + (wv << 4) + rrow) * 1024 + (m0 + mt * 16 + lr)];
        float pv = wvl * __expf(s[mt][reg] * 0.125f);
        den[reg] += pv;
        p_lds[((wv << 4) + rrow) * 72 + mt * 16 + lr] = f2bf(pv);
      }
    const unsigned short* pb = &p_lds[((wv << 4) + lr) * 72];
    bf16x8 pa0 = *(const bf16x8*)(pb + lq * 8);
    bf16x8 pa1 = *(const bf16x8*)(pb + 32 + lq * 8);
#pragma unroll
    for (int dt = 0; dt < 4; dt++) {
      int d = dt * 16 + lr;
      int sw = ((d >> 3) & 7) << 3;
      const unsigned short* vb = &v_lds[d * 72];
      acc[dt] = __builtin_amdgcn_mfma_f32_16x16x32_bf16(pa0, *(const bf16x8*)(vb + ((lq * 8) ^ sw)), acc[dt], 0, 0, 0);
      acc[dt] = __builtin_amdgcn_mfma_f32_16x16x32_bf16(pa1, *(const bf16x8*)(vb + ((32 + lq * 8) ^ sw)), acc[dt], 0, 0, 0);
    }
  }
#pragma unroll
  for (int off = 1; off < 16; off <<= 1)
#pragma unroll
    for (int reg = 0; reg < 4; reg++) den[reg] += __shfl_xor(den[reg], off);
#pragma unroll
  for (int dt = 0; dt < 4; dt++)
#pragma unroll
    for (int reg = 0; reg < 4; reg++) {
      size_t row = (size_t)((b << 10) + n0 + (wv << 4) + lq * 4 + reg);
      oh[row * 512 + (h << 6) + dt * 16 + lr] = acc[dt][reg] / den[reg];
    }
}

// ---------------------------------------------------------------------------
extern "C" void kernel_launch(void* const* d_in, const int* in_sizes, int n_in,
                              void* d_out, int out_size, void* d_ws, size_t ws_size,
                              hipStream_t stream) {
  (void)in_sizes; (void)n_in; (void)out_size; (void)ws_size;
  const float* x     = (const float*)d_in[0];
  const float* rpe   = (const float*)d_in[1];
  const float* wqkv  = (const float*)d_in[2];
  const float* wproj = (const float*)d_in[3];
  const float* bproj = (const float*)d_in[4];
  const float* c1w   = (const float*)d_in[5];
  // d_in[6] = c1b: cancels exactly in the following instance-norm
  const float* g1w   = (const float*)d_in[7];
  const float* g1b   = (const float*)d_in[8];
  const float* c2w   = (const float*)d_in[9];
  // d_in[10] = c2b: cancels likewise
  const float* g2w   = (const float*)d_in[11];
  const float* g2b   = (const float*)d_in[12];
  float* out = (float*)d_out;

  char* ws = (char*)d_ws;
  unsigned short* qkv_bf = (unsigned short*)ws;            // 25,165,824 B
  float* wppe = (float*)(ws + 25165824);                   // 33,554,432 B
  float* ohb  = (float*)(ws + 58720256);                   // 16,777,216 B

  // 1) qkv = x @ wqkv^T  -> bf16 (f16 MFMA)
  gemm_f16_bt<true><<<dim3(12, 64), 256, 0, stream>>>(x, wqkv, qkv_bf, nullptr, 8192, 1536, 512);

  // 2) fused conv1+IN+relu+conv2+IN+sigmoid -> w
  const int ldsC = 162048;
  hipFuncSetAttribute(reinterpret_cast<const void*>(&conv_fused),
                      hipFuncAttributeMaxDynamicSharedMemorySize, ldsC);
  conv_fused<<<1024, 1024, ldsC, stream>>>(rpe, c1w, g1w, g1b, c2w, g2w, g2b, wppe);

  // 3) fused attention
  attn_kernel<<<dim3(16, 64), 256, 0, stream>>>(qkv_bf, wppe, ohb);

  // 4) out = oh @ wproj^T + bproj (f16 MFMA)
  gemm_f16_bt<false><<<dim3(4, 64), 256, 0, stream>>>(ohb, wproj, out, bproj, 8192, 512, 512);
}

// Round 7
// 209.172 us; speedup vs baseline: 4.0212x; 1.0411x over previous
//
#include <hip/hip_runtime.h>
#include <hip/hip_fp16.h>

// MPA_16698832847132 — round 6:
//  conv_fused: conflict-free weight-fragment LDS layout (stride-40 rows in
//  consumer order; measured: ALL 1.66e7 conflict cycles were these reads),
//  w2f hoisted out of the conv2 tile loop (persistent wH2, loaded post-conv1).
// Workspace: qkv bf16 @0 (25,165,824) | w f32 @25,165,824 (33,554,432) | oh f32 @58,720,256 (16,777,216)

typedef __attribute__((ext_vector_type(8))) short bf16x8;
typedef __attribute__((ext_vector_type(8))) _Float16 f16x8;
typedef __attribute__((ext_vector_type(4))) float f32x4;

__device__ __forceinline__ unsigned short f2bf(float f) {
  unsigned u = __builtin_bit_cast(unsigned, f);
  u += 0x7FFFu + ((u >> 16) & 1u);
  return (unsigned short)(u >> 16);
}

// ---------------- C[M][N] = A[M][K] * B[N][K]^T (+bias), f16 MFMA --------------
// 128x128 tile, BK=32, 256 thr = 4 waves (2x2), per-wave 64x64 via 4x4 16x16 frags.
template<bool OUT_BF16>
__global__ __launch_bounds__(256) void gemm_f16_bt(
    const float* __restrict__ A, const float* __restrict__ B,
    void* __restrict__ Cv, const float* __restrict__ bias,
    int M, int N, int K)
{
  __shared__ __align__(16) _Float16 As[128 * 40];
  __shared__ __align__(16) _Float16 Bs[128 * 40];
  const int tid = threadIdx.x;
  const int wv = tid >> 6, ln = tid & 63, lr = ln & 15, lq = ln >> 4;
  const int wm = wv >> 1, wn = wv & 1;
  const int m0 = blockIdx.y * 128, n0 = blockIdx.x * 128;

  f32x4 acc[4][4];
#pragma unroll
  for (int i = 0; i < 4; i++)
#pragma unroll
    for (int j = 0; j < 4; j++) acc[i][j] = (f32x4){0.f, 0.f, 0.f, 0.f};

  const int sr = tid >> 1, sk = (tid & 1) * 16;
  const float* Ap = A + (size_t)(m0 + sr) * K + sk;
  const float* Bp = B + (size_t)(n0 + sr) * K + sk;

  for (int k0 = 0; k0 < K; k0 += 32) {
    float4 av0 = *(const float4*)(Ap + k0);
    float4 av1 = *(const float4*)(Ap + k0 + 4);
    float4 av2 = *(const float4*)(Ap + k0 + 8);
    float4 av3 = *(const float4*)(Ap + k0 + 12);
    float4 bv0 = *(const float4*)(Bp + k0);
    float4 bv1 = *(const float4*)(Bp + k0 + 4);
    float4 bv2 = *(const float4*)(Bp + k0 + 8);
    float4 bv3 = *(const float4*)(Bp + k0 + 12);
    __syncthreads();
    {
      f16x8 p0, p1, r0, r1;
      p0[0]=(_Float16)av0.x; p0[1]=(_Float16)av0.y; p0[2]=(_Float16)av0.z; p0[3]=(_Float16)av0.w;
      p0[4]=(_Float16)av1.x; p0[5]=(_Float16)av1.y; p0[6]=(_Float16)av1.z; p0[7]=(_Float16)av1.w;
      p1[0]=(_Float16)av2.x; p1[1]=(_Float16)av2.y; p1[2]=(_Float16)av2.z; p1[3]=(_Float16)av2.w;
      p1[4]=(_Float16)av3.x; p1[5]=(_Float16)av3.y; p1[6]=(_Float16)av3.z; p1[7]=(_Float16)av3.w;
      r0[0]=(_Float16)bv0.x; r0[1]=(_Float16)bv0.y; r0[2]=(_Float16)bv0.z; r0[3]=(_Float16)bv0.w;
      r0[4]=(_Float16)bv1.x; r0[5]=(_Float16)bv1.y; r0[6]=(_Float16)bv1.z; r0[7]=(_Float16)bv1.w;
      r1[0]=(_Float16)bv2.x; r1[1]=(_Float16)bv2.y; r1[2]=(_Float16)bv2.z; r1[3]=(_Float16)bv2.w;
      r1[4]=(_Float16)bv3.x; r1[5]=(_Float16)bv3.y; r1[6]=(_Float16)bv3.z; r1[7]=(_Float16)bv3.w;
      *(f16x8*)&As[sr * 40 + sk] = p0;
      *(f16x8*)&As[sr * 40 + sk + 8] = p1;
      *(f16x8*)&Bs[sr * 40 + sk] = r0;
      *(f16x8*)&Bs[sr * 40 + sk + 8] = r1;
    }
    __syncthreads();
    f16x8 af[4], bf[4];
#pragma unroll
    for (int mf = 0; mf < 4; mf++)
      af[mf] = *(const f16x8*)&As[(wm * 64 + mf * 16 + lr) * 40 + lq * 8];
#pragma unroll
    for (int nf = 0; nf < 4; nf++)
      bf[nf] = *(const f16x8*)&Bs[(wn * 64 + nf * 16 + lr) * 40 + lq * 8];
#pragma unroll
    for (int mf = 0; mf < 4; mf++)
#pragma unroll
      for (int nf = 0; nf < 4; nf++)
        acc[mf][nf] = __builtin_amdgcn_mfma_f32_16x16x32_f16(af[mf], bf[nf], acc[mf][nf], 0, 0, 0);
  }

#pragma unroll
  for (int mf = 0; mf < 4; mf++)
#pragma unroll
    for (int reg = 0; reg < 4; reg++) {
      const int row = m0 + wm * 64 + mf * 16 + lq * 4 + reg;
#pragma unroll
      for (int nf = 0; nf < 4; nf++) {
        const int col = n0 + wn * 64 + nf * 16 + lr;
        float v = acc[mf][nf][reg];
        if (bias) v += bias[col];
        if (OUT_BF16) ((unsigned short*)Cv)[(size_t)row * N + col] = f2bf(v);
        else          ((float*)Cv)[(size_t)row * N + col] = v;
      }
    }
}

// ---------------- fused conv1+IN+relu+conv2+IN+sigmoid, f16 MFMA ---------------
// One image per block (grid 1024), 1024 threads = 16 waves (4/SIMD).
// LDS map (bytes):
//   inA  [g][1296][8] f16   @0       (82,944)   [overlay transF f32[8][1032] in phase 2]
//   yB   [g][1156][8] f16   @82,944  (73,984)   [overlay wH1: 11,520 halves @82,944]
//   wH2  [9*8][40] f16      @156,928 (5,760)    persistent
//   statA f32[64]           @162,688 | aL/cL f32[32+32] @162,944 -> total 163,200
// Weight rows stride 40 halves, row index in CONSUMER order -> lane stride 20
// words mod 32 = 20 -> 8 distinct bank groups -> conflict-free fragment reads.
__global__ __launch_bounds__(1024, 1) void conv_fused(
    const float* __restrict__ rpe,
    const float* __restrict__ c1w, const float* __restrict__ g1, const float* __restrict__ b1,
    const float* __restrict__ c2w, const float* __restrict__ g2, const float* __restrict__ b2,
    float* __restrict__ wout)
{
  extern __shared__ __align__(16) char smem[];
  unsigned short* inA = (unsigned short*)smem;              // 4 x 10368 halves
  unsigned short* yB  = (unsigned short*)(smem + 82944);    // 4 x 9248 halves
  unsigned short* wH1 = yB;                                 // overlay: [tap][ct*16+r][40]
  unsigned short* wH2 = (unsigned short*)(smem + 156928);   // [tap*8+oc][40] persistent
  float* statA = (float*)(smem + 162688);                   // 64
  float* aL    = (float*)(smem + 162944);                   // 32
  float* cL    = aL + 32;                                   // 32
  float* transF = (float*)smem;                             // phase-2 overlay [8][1032]

  const int tid = threadIdx.x;
  const int wv = tid >> 6, ln = tid & 63;
  const int lr = ln & 15, lq = ln >> 4;
  const int p = blockIdx.x;

  if (tid < 64) statA[tid] = 0.f;

  // ---- stage input: rpe crop -> LDS f16 channel-major [g][pix][8]
  const float* src = rpe + (size_t)(((p >> 5) + 2) * 36 + (p & 31) + 2) * 41472;
  for (int t = tid; t < 10368; t += 1024) {
    int pix = t >> 3, dq = (t & 7) << 2;
    float4 v = *(const float4*)(src + pix * 32 + dq);
    __half2 h0 = __floats2half2_rn(v.x, v.y);
    __half2 h1 = __floats2half2_rn(v.z, v.w);
    uint2 u; u.x = __builtin_bit_cast(unsigned, h0); u.y = __builtin_bit_cast(unsigned, h1);
    *(uint2*)&inA[(dq >> 3) * 10368 + pix * 8 + (dq & 7)] = u;
  }
  // ---- stage weights coalesced -> LDS f16, stride-40 rows in consumer order
  for (int t = tid; t < 9216; t += 1024) {
    int oc = t / 288, rem = t - oc * 288;
    int ic = rem / 9, tap = rem - ic * 9;
    wH1[(tap * 32 + (oc & 1) * 16 + (oc >> 1)) * 40 + ic] = __half_as_ushort(__float2half(c1w[t]));
  }
  for (int t = tid; t < 2304; t += 1024) {
    int oc = t / 288, rem = t - oc * 288;
    int ic = rem / 9, tap = rem - ic * 9;
    wH2[(tap * 8 + oc) * 40 + ic] = __half_as_ushort(__float2half(c2w[t]));
  }
  __syncthreads();

  // ---- w1 fragments (lane lr holds oc=2*lr+ct; row = ct*16+lr -> stride 40 halves)
  f16x8 w1f[2][9];
  const int ic0 = lq * 8;
#pragma unroll
  for (int ct = 0; ct < 2; ct++)
#pragma unroll
    for (int tap = 0; tap < 9; tap++)
      w1f[ct][tap] = *(const f16x8*)&wH1[(tap * 32 + ct * 16 + lr) * 40 + ic0];
  __syncthreads();  // wH1 reads done before conv1 overwrites yB

  // ---- conv1: 73 row-tiles of 16 out-pixels, K=288, N=32
  constexpr int OFF1[9] = {0, 8, 16, 288, 296, 304, 576, 584, 592};
  float s0 = 0.f, q0 = 0.f, s1 = 0.f, q1 = 0.f;
  const unsigned short* inAg = inA + lq * 10368;
  for (int t = wv; t < 73; t += 16) {
    int m = t * 16 + lr;
    int ms = m < 1155 ? m : 1155;
    const unsigned short* ab = inAg + ((ms / 34) * 36 + (ms % 34)) * 8;
    f32x4 c0 = {0.f, 0.f, 0.f, 0.f}, c1v = {0.f, 0.f, 0.f, 0.f};
#pragma unroll
    for (int tap = 0; tap < 9; tap++) {
      f16x8 av = *(const f16x8*)(ab + OFF1[tap]);
      c0  = __builtin_amdgcn_mfma_f32_16x16x32_f16(av, w1f[0][tap], c0, 0, 0, 0);
      c1v = __builtin_amdgcn_mfma_f32_16x16x32_f16(av, w1f[1][tap], c1v, 0, 0, 0);
    }
#pragma unroll
    for (int r = 0; r < 4; r++) {
      int mo = t * 16 + lq * 4 + r;
      if (mo < 1156) {
        float v0 = c0[r], v1 = c1v[r];   // logical channels 2*lr, 2*lr+1
        unsigned u = (unsigned)__half_as_ushort(__float2half(v0))
                   | ((unsigned)__half_as_ushort(__float2half(v1)) << 16);
        *(unsigned*)&yB[(lr >> 2) * 9248 + mo * 8 + ((lr * 2) & 7)] = u;
        s0 += v0; q0 += v0 * v0; s1 += v1; q1 += v1 * v1;
      }
    }
  }
#pragma unroll
  for (int off = 16; off < 64; off <<= 1) {
    s0 += __shfl_xor(s0, off); q0 += __shfl_xor(q0, off);
    s1 += __shfl_xor(s1, off); q1 += __shfl_xor(q1, off);
  }
  if (ln < 16) {
    atomicAdd(&statA[ln], s0);      atomicAdd(&statA[16 + ln], q0);
    atomicAdd(&statA[32 + ln], s1); atomicAdd(&statA[48 + ln], q1);
  }
  __syncthreads();
  if (tid < 32) {
    int cti = tid >> 4, lri = tid & 15;   // cti=0: ch=2*lri (s0/q0), cti=1: ch=2*lri+1
    float s = statA[cti * 32 + lri];
    float q = statA[cti * 32 + 16 + lri];
    int ch = 2 * lri + cti;
    float mu = s * (1.f / 1156.f);
    float var = q * (1.f / 1156.f) - mu * mu;
    float a_ = rsqrtf(var + 1e-5f) * g1[ch];
    aL[ch] = a_; cL[ch] = b1[ch] - mu * a_;
  }
  if (tid < 16) statA[tid] = 0.f;  // conv2 stat slots (same-thread program order safe)
  __syncthreads();

  // ---- normalize + relu, in-place RMW on yB (channel-major)
  {
    int g = tid >> 8, ocb = g * 8;
    unsigned short* yg = yB + g * 9248;
    for (int pix = (tid & 255); pix < 1156; pix += 256) {
      f16x8 raw = *(const f16x8*)&yg[pix * 8];
      f16x8 outv;
#pragma unroll
      for (int e = 0; e < 8; e++) {
        float v = (float)raw[e];
        v = fmaxf(v * aL[ocb + e] + cL[ocb + e], 0.f);
        outv[e] = (_Float16)v;
      }
      *(f16x8*)&yg[pix * 8] = outv;
    }
  }
  __syncthreads();

  // ---- conv2: w2 fragments once (w1f dead -> VGPR peak stays <=128), then tiles
  f16x8 w2f[9];
#pragma unroll
  for (int tap = 0; tap < 9; tap++)
    w2f[tap] = *(const f16x8*)&wH2[(tap * 8 + (lr & 7)) * 40 + ic0];

  constexpr int OFF2[9] = {0, 8, 16, 272, 280, 288, 544, 552, 560};
  const unsigned short* yBg = yB + lq * 9248;
  float s2 = 0.f, q2 = 0.f;
  for (int t = wv; t < 64; t += 16) {
    int m = t * 16 + lr;
    const unsigned short* ab = yBg + ((m >> 5) * 34 + (m & 31)) * 8;
    f32x4 cc = {0.f, 0.f, 0.f, 0.f};
#pragma unroll
    for (int tap = 0; tap < 9; tap++) {
      f16x8 av = *(const f16x8*)(ab + OFF2[tap]);
      cc = __builtin_amdgcn_mfma_f32_16x16x32_f16(av, w2f[tap], cc, 0, 0, 0);
    }
#pragma unroll
    for (int r = 0; r < 4; r++) {
      int mo = t * 16 + lq * 4 + r;
      float v = cc[r];
      if (lr < 8) {
        s2 += v; q2 += v * v;
        transF[lr * 1032 + mo] = v;
      }
    }
  }
#pragma unroll
  for (int off = 16; off < 64; off <<= 1) {
    s2 += __shfl_xor(s2, off); q2 += __shfl_xor(q2, off);
  }
  if (ln < 8) { atomicAdd(&statA[ln], s2); atomicAdd(&statA[8 + ln], q2); }
  __syncthreads();
  if (tid < 8) {
    float s = statA[tid], q = statA[8 + tid];
    float mu = s * (1.f / 1024.f);
    float var = q * (1.f / 1024.f) - mu * mu;
    float a_ = rsqrtf(var + 1e-5f) * g2[tid];
    aL[tid] = a_; cL[tid] = b2[tid] - mu * a_;
  }
  __syncthreads();

  // ---- sigmoid + coalesced store: wout[oc][p][pix]
  for (int idx = tid; idx < 2048; idx += 1024) {
    int oc = idx >> 8, p4 = (idx & 255) << 2;
    float4 v = *(const float4*)&transF[oc * 1032 + p4];
    float a_ = aL[oc], c_ = cL[oc];
    float4 o;
    o.x = 1.f / (1.f + __expf(-(v.x * a_ + c_)));
    o.y = 1.f / (1.f + __expf(-(v.y * a_ + c_)));
    o.z = 1.f / (1.f + __expf(-(v.z * a_ + c_)));
    o.w = 1.f / (1.f + __expf(-(v.w * a_ + c_)));
    *(float4*)(wout + ((size_t)oc << 20) + ((size_t)p << 10) + p4) = o;
  }
}

// ---------------- fused attention, bf16 MFMA 16x16x32 -------------------------
__global__ __launch_bounds__(256) void attn_kernel(
    const unsigned short* __restrict__ qkv,  // bf16 bits [8192][1536]
    const float* __restrict__ wppe,          // [8][1024][1024]
    float* __restrict__ oh)                  // [8192][512] = (b,n,h,d)
{
  __shared__ __align__(16) unsigned short k_lds[64 * 72];
  __shared__ __align__(16) unsigned short v_lds[64 * 72]; // transposed [d][m ^ swz]
  __shared__ __align__(16) unsigned short p_lds[4 * 16 * 72];
  const int tid = threadIdx.x;
  const int wv = tid >> 6, ln = tid & 63;
  const int lr = ln & 15, lq = ln >> 4;
  const int b = blockIdx.y >> 3, h = blockIdx.y & 7;
  const int n0 = blockIdx.x << 6;

  const size_t qoff = (size_t)((b << 10) + n0 + (wv << 4) + lr) * 1536 + (h << 6);
  bf16x8 qf0 = *(const bf16x8*)(qkv + qoff + lq * 8);
  bf16x8 qf1 = *(const bf16x8*)(qkv + qoff + 32 + lq * 8);

  f32x4 acc[4];
#pragma unroll
  for (int dt = 0; dt < 4; dt++) acc[dt] = (f32x4){0.f, 0.f, 0.f, 0.f};
  float den[4] = {0.f, 0.f, 0.f, 0.f};
  const float* wp = wppe + ((size_t)h << 20);

  for (int m0 = 0; m0 < 1024; m0 += 64) {
    __syncthreads();
    for (int t = tid; t < 512; t += 256) {
      int m = t >> 3, dq = t & 7;
      const unsigned short* kr = qkv + (size_t)((b << 10) + m0 + m) * 1536 + 512 + (h << 6) + dq * 8;
      *(uint4*)&k_lds[m * 72 + dq * 8] = *(const uint4*)kr;
      uint4 vvv = *(const uint4*)(kr + 512);
      unsigned short tmp[8];
      *(uint4*)tmp = vvv;
#pragma unroll
      for (int i = 0; i < 8; i++) {
        int d = dq * 8 + i;
        v_lds[d * 72 + (m ^ (((d >> 3) & 7) << 3))] = tmp[i];
      }
    }
    __syncthreads();

    f32x4 s[4];
#pragma unroll
    for (int mt = 0; mt < 4; mt++) {
      const unsigned short* kb = &k_lds[(mt * 16 + lr) * 72 + lq * 8];
      f32x4 cz = (f32x4){0.f, 0.f, 0.f, 0.f};
      cz = __builtin_amdgcn_mfma_f32_16x16x32_bf16(qf0, *(const bf16x8*)kb, cz, 0, 0, 0);
      cz = __builtin_amdgcn_mfma_f32_16x16x32_bf16(qf1, *(const bf16x8*)(kb + 32), cz, 0, 0, 0);
      s[mt] = cz;
    }
#pragma unroll
    for (int mt = 0; mt < 4; mt++)
#pragma unroll
      for (int reg = 0; reg < 4; reg++) {
        int rrow = lq * 4 + reg;
        float wvl = wp[(size_t)(n0 + (wv << 4) + rrow) * 1024 + (m0 + mt * 16 + lr)];
        float pv = wvl * __expf(s[mt][reg] * 0.125f);
        den[reg] += pv;
        p_lds[((wv << 4) + rrow) * 72 + mt * 16 + lr] = f2bf(pv);
      }
    const unsigned short* pb = &p_lds[((wv << 4) + lr) * 72];
    bf16x8 pa0 = *(const bf16x8*)(pb + lq * 8);
    bf16x8 pa1 = *(const bf16x8*)(pb + 32 + lq * 8);
#pragma unroll
    for (int dt = 0; dt < 4; dt++) {
      int d = dt * 16 + lr;
      int sw = ((d >> 3) & 7) << 3;
      const unsigned short* vb = &v_lds[d * 72];
      acc[dt] = __builtin_amdgcn_mfma_f32_16x16x32_bf16(pa0, *(const bf16x8*)(vb + ((lq * 8) ^ sw)), acc[dt], 0, 0, 0);
      acc[dt] = __builtin_amdgcn_mfma_f32_16x16x32_bf16(pa1, *(const bf16x8*)(vb + ((32 + lq * 8) ^ sw)), acc[dt], 0, 0, 0);
    }
  }
#pragma unroll
  for (int off = 1; off < 16; off <<= 1)
#pragma unroll
    for (int reg = 0; reg < 4; reg++) den[reg] += __shfl_xor(den[reg], off);
#pragma unroll
  for (int dt = 0; dt < 4; dt++)
#pragma unroll
    for (int reg = 0; reg < 4; reg++) {
      size_t row = (size_t)((b << 10) + n0 + (wv << 4) + lq * 4 + reg);
      oh[row * 512 + (h << 6) + dt * 16 + lr] = acc[dt][reg] / den[reg];
    }
}

// ---------------------------------------------------------------------------
extern "C" void kernel_launch(void* const* d_in, const int* in_sizes, int n_in,
                              void* d_out, int out_size, void* d_ws, size_t ws_size,
                              hipStream_t stream) {
  (void)in_sizes; (void)n_in; (void)out_size; (void)ws_size;
  const float* x     = (const float*)d_in[0];
  const float* rpe   = (const float*)d_in[1];
  const float* wqkv  = (const float*)d_in[2];
  const float* wproj = (const float*)d_in[3];
  const float* bproj = (const float*)d_in[4];
  const float* c1w   = (const float*)d_in[5];
  // d_in[6] = c1b: cancels exactly in the following instance-norm
  const float* g1w   = (const float*)d_in[7];
  const float* g1b   = (const float*)d_in[8];
  const float* c2w   = (const float*)d_in[9];
  // d_in[10] = c2b: cancels likewise
  const float* g2w   = (const float*)d_in[11];
  const float* g2b   = (const float*)d_in[12];
  float* out = (float*)d_out;

  char* ws = (char*)d_ws;
  unsigned short* qkv_bf = (unsigned short*)ws;            // 25,165,824 B
  float* wppe = (float*)(ws + 25165824);                   // 33,554,432 B
  float* ohb  = (float*)(ws + 58720256);                   // 16,777,216 B

  // 1) qkv = x @ wqkv^T  -> bf16 (f16 MFMA)
  gemm_f16_bt<true><<<dim3(12, 64), 256, 0, stream>>>(x, wqkv, qkv_bf, nullptr, 8192, 1536, 512);

  // 2) fused conv1+IN+relu+conv2+IN+sigmoid -> w
  const int ldsC = 163200;
  hipFuncSetAttribute(reinterpret_cast<const void*>(&conv_fused),
                      hipFuncAttributeMaxDynamicSharedMemorySize, ldsC);
  conv_fused<<<1024, 1024, ldsC, stream>>>(rpe, c1w, g1w, g1b, c2w, g2w, g2b, wppe);

  // 3) fused attention
  attn_kernel<<<dim3(16, 64), 256, 0, stream>>>(qkv_bf, wppe, ohb);

  // 4) out = oh @ wproj^T + bproj (f16 MFMA)
  gemm_f16_bt<false><<<dim3(4, 64), 256, 0, stream>>>(ohb, wproj, out, bproj, 8192, 512, 512);
}